// Round 11
// baseline (647.883 us; speedup 1.0000x reference)
//
#include <hip/hip_runtime.h>
#include <hip/hip_bf16.h>

#define B_  8
#define L_  512
#define DM  512
#define NL  4
#define DS  16
#define HOR 96
#define DC  4
#define DI  1024
#define DTR 32

#define CHUNK 16
#define NCHK (L_/CHUNK)   // 32

typedef __bf16 bf16_t;
typedef __bf16 b8_t __attribute__((ext_vector_type(8)));
typedef float  f4_t __attribute__((ext_vector_type(4)));

#define LOG2E 1.44269504088896f

__device__ __forceinline__ float sigmoidf_(float x){ return 1.f/(1.f+__expf(-x)); }

__device__ __forceinline__ void async16(const bf16_t* g, bf16_t* l){
  __builtin_amdgcn_global_load_lds((const __attribute__((address_space(1))) void*)g,
                                   (__attribute__((address_space(3))) void*)l, 16, 0, 0);
}

// ---------- fused f32 -> bf16 weight convert ----------
__global__ __launch_bounds__(256) void k_cvtall(const float* __restrict__ p0, bf16_t* __restrict__ o0,
                                                const float* __restrict__ p1, bf16_t* __restrict__ o1,
                                                const float* __restrict__ p2, bf16_t* __restrict__ o2,
                                                const float* __restrict__ p3, bf16_t* __restrict__ o3){
  int j = blockIdx.x*256 + threadIdx.x;   // v4 index
  const int S0=1048576, S1=65536, S2=32768;
  const float* src; bf16_t* dst;
  if (j < S0){ src=p0; dst=o0; }
  else if ((j-=S0) < S1){ src=p1; dst=o1; }
  else if ((j-=S1) < S2){ src=p2; dst=o2; }
  else { j-=S2; src=p3; dst=o3; }
  f4_t v = ((const f4_t*)src)[j];
  bf16_t* o = dst + (size_t)j*4;
  o[0]=(bf16_t)v[0]; o[1]=(bf16_t)v[1]; o[2]=(bf16_t)v[2]; o[3]=(bf16_t)v[3];
}

// ---------- embed (+ layer-0 sumsq atomics) ----------
__global__ __launch_bounds__(256) void k_embed(const float* __restrict__ x, const float* __restrict__ ew,
                                               const float* __restrict__ eb, float* __restrict__ h,
                                               float* __restrict__ sumsq0){
  int idx = blockIdx.x*256 + threadIdx.x;   // B*L*DM
  int d = idx & (DM-1); int t = idx >> 9;
  float v = x[t]*ew[d] + eb[d];
  h[idx] = v;
  float s = v*v;
  #pragma unroll
  for (int m=32;m;m>>=1) s += __shfl_xor(s, m);
  if ((threadIdx.x&63)==0) atomicAdd(sumsq0 + t, s);
}

// ---------- in_proj GEMM with fused rmsnorm scaling on A staging ----------
// xz(bf16) = rmsnorm(h) @ Wi^T ; grid (2*DI/128, M/64)
__global__ __launch_bounds__(256) void k_gin(const float* __restrict__ h, const float* __restrict__ sumsq,
                                             const float* __restrict__ nw, const bf16_t* __restrict__ Wi,
                                             bf16_t* __restrict__ xzbf){
  __shared__ bf16_t As[64*32];
  __shared__ bf16_t Ws[128*32];
  int tid = threadIdx.x;
  int m0 = blockIdx.y*64, n0 = blockIdx.x*128;
  int wave = tid>>6, lane = tid&63;
  int wm = (wave>>1)*32, wn = (wave&1)*64;
  int lr = lane&15, q = lane>>4;
  int r0 = tid>>2, c0 = (tid&3)*8;
  float sc = rsqrtf(sumsq[m0+r0]*(1.f/DM) + 1e-5f);
  const float* hrow = h + (size_t)(m0+r0)*DM;
  f4_t acc[2][4] = {};
  for (int k0=0;k0<DM;k0+=32){
    f4_t v0 = *(const f4_t*)(hrow + k0 + c0);
    f4_t v1 = *(const f4_t*)(hrow + k0 + c0 + 4);
    f4_t w0 = *(const f4_t*)(nw + k0 + c0);
    f4_t w1 = *(const f4_t*)(nw + k0 + c0 + 4);
    b8_t av;
    #pragma unroll
    for (int c=0;c<4;c++){ av[c]=(bf16_t)(v0[c]*sc*w0[c]); av[4+c]=(bf16_t)(v1[c]*sc*w1[c]); }
    *(b8_t*)(As + tid*8) = av;
    async16(Wi + (size_t)(n0+r0)*DM + k0 + c0,    Ws + tid*8);
    async16(Wi + (size_t)(n0+r0+64)*DM + k0 + c0, Ws + tid*8 + 2048);
    __syncthreads();
    b8_t a[2], b[4];
    #pragma unroll
    for (int i=0;i<2;i++) a[i] = *(const b8_t*)(As + (wm+i*16+lr)*32 + q*8);
    #pragma unroll
    for (int j=0;j<4;j++) b[j] = *(const b8_t*)(Ws + (wn+j*16+lr)*32 + q*8);
    #pragma unroll
    for (int i=0;i<2;i++)
      #pragma unroll
      for (int j=0;j<4;j++)
        acc[i][j] = __builtin_amdgcn_mfma_f32_16x16x32_bf16(a[i], b[j], acc[i][j], 0,0,0);
    __syncthreads();
  }
  #pragma unroll
  for (int i=0;i<2;i++)
  #pragma unroll
  for (int j=0;j<4;j++){
    int col = n0 + wn + j*16 + lr;
    int rb  = m0 + wm + i*16 + q*4;
    #pragma unroll
    for (int r=0;r<4;r++)
      xzbf[(size_t)(rb+r)*(2*DI) + col] = (bf16_t)acc[i][j][r];
  }
}

// ---------- out_proj GEMM: h += y @ Wo^T, epilogue emits next-layer sumsq atomics ----------
__global__ __launch_bounds__(256) void k_gout(const bf16_t* __restrict__ A,
                                              const bf16_t* __restrict__ W,
                                              float* __restrict__ C,
                                              float* __restrict__ snext){
  __shared__ bf16_t As[64*32];
  __shared__ bf16_t Ws[64*32];
  int tid = threadIdx.x;
  int m0 = blockIdx.y*64, n0 = blockIdx.x*64;
  int wave = tid>>6, lane = tid&63;
  int wm = (wave>>1)*32, wn = (wave&1)*32;
  int lr = lane&15, q = lane>>4;
  int e0 = tid*8, r0 = e0>>5, c0 = e0&31;
  f4_t acc[2][2] = {};
  for (int k0=0;k0<DI;k0+=32){
    async16(A + (size_t)(m0+r0)*DI + k0 + c0, As + e0);
    async16(W + (size_t)(n0+r0)*DI + k0 + c0, Ws + e0);
    __syncthreads();
    b8_t a[2], b[2];
    #pragma unroll
    for (int i=0;i<2;i++) a[i] = *(const b8_t*)(As + (wm+i*16+lr)*32 + q*8);
    #pragma unroll
    for (int j=0;j<2;j++) b[j] = *(const b8_t*)(Ws + (wn+j*16+lr)*32 + q*8);
    #pragma unroll
    for (int i=0;i<2;i++)
      #pragma unroll
      for (int j=0;j<2;j++)
        acc[i][j] = __builtin_amdgcn_mfma_f32_16x16x32_bf16(a[i], b[j], acc[i][j], 0,0,0);
    __syncthreads();
  }
  float ssv[2][4] = {};
  #pragma unroll
  for (int i=0;i<2;i++)
  #pragma unroll
  for (int j=0;j<2;j++){
    int col = n0 + wn + j*16 + lr;
    int rb  = m0 + wm + i*16 + q*4;
    #pragma unroll
    for (int r=0;r<4;r++){
      size_t off = (size_t)(rb+r)*DM + col;
      float v = C[off] + acc[i][j][r];
      C[off] = v;
      ssv[i][r] += v*v;
    }
  }
  #pragma unroll
  for (int i=0;i<2;i++)
  #pragma unroll
  for (int r=0;r<4;r++){
    float s = ssv[i][r];
    s += __shfl_xor(s, 1); s += __shfl_xor(s, 2);
    s += __shfl_xor(s, 4); s += __shfl_xor(s, 8);
    if (lr == 0) atomicAdd(snext + m0 + wm + i*16 + q*4 + r, s);
  }
}

// ---------- x_proj GEMM with conv+silu fused into A staging (split-K x8); also emits xinbf ----------
__global__ __launch_bounds__(256) void k_dbc(const bf16_t* __restrict__ xzbf, const float* __restrict__ cw,
                                             const float* __restrict__ cb, const bf16_t* __restrict__ wxp,
                                             float* __restrict__ part, bf16_t* __restrict__ xinbf){
  __shared__ bf16_t As[64*32];
  __shared__ bf16_t Ws[64*32];
  int tid = threadIdx.x;
  int m0 = blockIdx.x*64;
  int z = blockIdx.y;
  int kbase = z*128;
  int wave = tid>>6, lane = tid&63;
  int wm = (wave>>1)*32, wn = (wave&1)*32;
  int lr = lane&15, q = lane>>4;
  int e0 = tid*8, r0 = e0>>5, c0 = e0&31;
  int gt = m0 + r0;              // global token
  int l  = gt & (L_-1);          // position within batch
  f4_t acc[2][2] = {};
  for (int k0=0;k0<128;k0+=32){
    int ch = kbase + k0 + c0;    // 8 channels ch..ch+7
    float cv[8];
    #pragma unroll
    for (int c=0;c<8;c++) cv[c] = cb[ch+c];
    #pragma unroll
    for (int k=0;k<DC;k++){
      if (l + k - (DC-1) >= 0){
        b8_t xv = *(const b8_t*)(xzbf + (size_t)(gt + k - (DC-1))*(2*DI) + ch);
        #pragma unroll
        for (int c=0;c<8;c++) cv[c] += (float)xv[c] * cw[(ch+c)*DC + k];
      }
    }
    b8_t av;
    #pragma unroll
    for (int c=0;c<8;c++){ float s = cv[c]*sigmoidf_(cv[c]); av[c] = (bf16_t)s; }
    *(b8_t*)(As + e0) = av;
    *(b8_t*)(xinbf + (size_t)gt*DI + ch) = av;     // each (token,channel) written once
    async16(wxp + (size_t)r0*DI + kbase + k0 + c0, Ws + e0);
    __syncthreads();
    b8_t a[2], b[2];
    #pragma unroll
    for (int i=0;i<2;i++) a[i] = *(const b8_t*)(As + (wm+i*16+lr)*32 + q*8);
    #pragma unroll
    for (int j=0;j<2;j++) b[j] = *(const b8_t*)(Ws + (wn+j*16+lr)*32 + q*8);
    #pragma unroll
    for (int i=0;i<2;i++)
      #pragma unroll
      for (int j=0;j<2;j++)
        acc[i][j] = __builtin_amdgcn_mfma_f32_16x16x32_bf16(a[i], b[j], acc[i][j], 0,0,0);
    __syncthreads();
  }
  float* P = part + (size_t)z*(B_*L_*64);
  #pragma unroll
  for (int i=0;i<2;i++)
  #pragma unroll
  for (int j=0;j<2;j++){
    int col = wn + j*16 + lr;
    int rb  = m0 + wm + i*16 + q*4;
    #pragma unroll
    for (int r=0;r<4;r++) P[(size_t)(rb+r)*64 + col] = acc[i][j][r];
  }
}

// ---------- fused: partial-reduce(x8) + dt-proj + softplus -> delta bf16; n-block0 writes dbc B/C f32 ----------
__global__ __launch_bounds__(256) void k_dt(const float* __restrict__ part, const bf16_t* __restrict__ wdt,
                                            const float* __restrict__ dtb, float* __restrict__ dbc,
                                            bf16_t* __restrict__ delta){
  __shared__ bf16_t As[64*32];
  __shared__ bf16_t Ws[64*32];
  int tid = threadIdx.x;
  int m0 = blockIdx.y*64, n0 = blockIdx.x*64;
  const size_t S = (size_t)B_*L_*64;
  int r0 = tid>>2, c0 = (tid&3)*8;
  int gt = m0 + r0;
  size_t base = (size_t)gt*64 + c0;
  f4_t s0 = *(const f4_t*)(part + base);
  f4_t s1 = *(const f4_t*)(part + base + 4);
  #pragma unroll
  for (int z=1;z<8;z++){
    s0 += *(const f4_t*)(part + z*S + base);
    s1 += *(const f4_t*)(part + z*S + base + 4);
  }
  b8_t av;
  #pragma unroll
  for (int c=0;c<4;c++){ av[c] = (bf16_t)s0[c]; av[4+c] = (bf16_t)s1[c]; }
  *(b8_t*)(As + tid*8) = av;
  if (n0 == 0){   // reduce + store B/C columns (32..64) in f32
    f4_t t0 = *(const f4_t*)(part + base + 32);
    f4_t t1 = *(const f4_t*)(part + base + 36);
    #pragma unroll
    for (int z=1;z<8;z++){
      t0 += *(const f4_t*)(part + z*S + base + 32);
      t1 += *(const f4_t*)(part + z*S + base + 36);
    }
    *(f4_t*)(dbc + base + 32) = t0;
    *(f4_t*)(dbc + base + 36) = t1;
  }
  async16(wdt + (size_t)(n0+r0)*DTR + c0, Ws + tid*8);
  __syncthreads();
  int wave = tid>>6, lane = tid&63;
  int wm = (wave>>1)*32, wn = (wave&1)*32;
  int lr = lane&15, q = lane>>4;
  b8_t a[2], b[2];
  #pragma unroll
  for (int i=0;i<2;i++) a[i] = *(const b8_t*)(As + (wm+i*16+lr)*32 + q*8);
  #pragma unroll
  for (int j=0;j<2;j++) b[j] = *(const b8_t*)(Ws + (wn+j*16+lr)*32 + q*8);
  f4_t acc[2][2] = {};
  #pragma unroll
  for (int i=0;i<2;i++)
    #pragma unroll
    for (int j=0;j<2;j++)
      acc[i][j] = __builtin_amdgcn_mfma_f32_16x16x32_bf16(a[i], b[j], acc[i][j], 0,0,0);
  #pragma unroll
  for (int i=0;i<2;i++)
  #pragma unroll
  for (int j=0;j<2;j++){
    int col = n0 + wn + j*16 + lr;
    int rb  = m0 + wm + i*16 + q*4;
    #pragma unroll
    for (int r=0;r<4;r++){
      float xv = acc[i][j][r] + dtb[col];
      float v = (xv>20.f)?xv:log1pf(__expf(xv));
      delta[(size_t)(rb+r)*DI + col] = (bf16_t)v;
    }
  }
}

// ---------- scan phase 1: LDS-staged chunk-local scan (h_in=0); bf16 state out ----------
__global__ __launch_bounds__(256) void k_scan_p1(const bf16_t* __restrict__ delta, const bf16_t* __restrict__ xin,
                                                 const float* __restrict__ dbc, const float* __restrict__ Alog,
                                                 bf16_t* __restrict__ hend, bf16_t* __restrict__ aprod){
  __shared__ bf16_t des[CHUNK][256];
  __shared__ bf16_t xs[CHUNK][256];
  __shared__ float Bs[CHUNK][DS];
  int tid = threadIdx.x;
  int blk = blockIdx.x;
  int chgrp = blk & 3;
  int chunk = (blk>>2) & (NCHK-1);
  int b = blk >> 7;
  int ch0 = chgrp<<8;
  int ch = ch0 + tid;
  int t0 = (b<<9) + chunk*CHUNK;
  #pragma unroll
  for (int idx=tid; idx<CHUNK*32; idx+=256){
    int row = idx>>5, c = (idx&31)*8;
    *(b8_t*)(&des[row][c]) = *(const b8_t*)(delta + (size_t)(t0+row)*DI + ch0 + c);
    *(b8_t*)(&xs[row][c])  = *(const b8_t*)(xin   + (size_t)(t0+row)*DI + ch0 + c);
  }
  {
    int ll = tid>>4, n = tid&15;
    Bs[ll][n] = dbc[(t0+ll)*64 + DTR + n];
  }
  __syncthreads();
  float An2[DS], h[DS];
  const f4_t* Ap = (const f4_t*)(Alog + ch*DS);
  #pragma unroll
  for (int v=0;v<4;v++){
    f4_t a4 = Ap[v];
    #pragma unroll
    for (int k=0;k<4;k++){ An2[v*4+k] = -__expf(a4[k])*LOG2E; h[v*4+k]=0.f; }
  }
  float sde = 0.f;
  #pragma unroll
  for (int l=0;l<CHUNK;l++){
    float de = (float)des[l][tid];
    float xv = (float)xs[l][tid];
    float dx = de*xv;
    sde += de;
    #pragma unroll
    for (int n=0;n<DS;n++){
      float dA = exp2f(de*An2[n]);
      h[n] = dA*h[n] + dx*Bs[l][n];
    }
  }
  size_t base = ((size_t)chunk*(B_*DI) + (b<<10) + ch)*DS;
  b8_t hv[2], av[2];
  #pragma unroll
  for (int v=0;v<2;v++)
    #pragma unroll
    for (int k=0;k<8;k++){
      hv[v][k] = (bf16_t)h[v*8+k];
      av[v][k] = (bf16_t)exp2f(An2[v*8+k]*sde);
    }
  ((b8_t*)(hend + base))[0] = hv[0]; ((b8_t*)(hend + base))[1] = hv[1];
  ((b8_t*)(aprod + base))[0] = av[0]; ((b8_t*)(aprod + base))[1] = av[1];
}

// ---------- scan phase 2: combine chunk transitions (bf16 in, bf16 hin out into aprod) ----------
__global__ __launch_bounds__(256) void k_scan_p2(const bf16_t* __restrict__ hend, bf16_t* __restrict__ ap_hin){
  int g = blockIdx.x*256 + threadIdx.x;   // B_*DI*DS
  float h = 0.f;
  for (int c=0;c<NCHK;c++){
    size_t off = (size_t)c*(B_*DI*DS) + g;
    float a = (float)ap_hin[off];
    float e = (float)hend[off];
    ap_hin[off] = (bf16_t)h;
    h = a*h + e;
  }
}

// ---------- scan phase 3: LDS-staged rerun with h_in, produce gated y (bf16) ----------
__global__ __launch_bounds__(256) void k_scan_p3(const bf16_t* __restrict__ delta, const bf16_t* __restrict__ xz,
                                                 const bf16_t* __restrict__ xin,
                                                 const float* __restrict__ dbc, const float* __restrict__ Alog,
                                                 const bf16_t* __restrict__ hin, const float* __restrict__ Dp,
                                                 bf16_t* __restrict__ ybf){
  __shared__ bf16_t des[CHUNK][256];
  __shared__ bf16_t xs[CHUNK][256];
  __shared__ bf16_t zs[CHUNK][256];
  __shared__ float Bs[CHUNK][DS];
  __shared__ float Cs[CHUNK][DS];
  int tid = threadIdx.x;
  int blk = blockIdx.x;
  int chgrp = blk & 3;
  int chunk = (blk>>2) & (NCHK-1);
  int b = blk >> 7;
  int ch0 = chgrp<<8;
  int ch = ch0 + tid;
  int t0 = (b<<9) + chunk*CHUNK;
  #pragma unroll
  for (int idx=tid; idx<CHUNK*32; idx+=256){
    int row = idx>>5, c = (idx&31)*8;
    *(b8_t*)(&des[row][c]) = *(const b8_t*)(delta + (size_t)(t0+row)*DI + ch0 + c);
    *(b8_t*)(&xs[row][c])  = *(const b8_t*)(xin   + (size_t)(t0+row)*DI + ch0 + c);
    *(b8_t*)(&zs[row][c])  = *(const b8_t*)(xz + (size_t)(t0+row)*(2*DI) + DI + ch0 + c);
  }
  {
    int ll = tid>>4, n = tid&15;
    Bs[ll][n] = dbc[(t0+ll)*64 + DTR + n];
    Cs[ll][n] = dbc[(t0+ll)*64 + DTR + DS + n];
  }
  __syncthreads();
  float An2[DS], h[DS];
  const f4_t* Ap = (const f4_t*)(Alog + ch*DS);
  size_t base = ((size_t)chunk*(B_*DI) + (b<<10) + ch)*DS;
  b8_t h0 = ((const b8_t*)(hin + base))[0];
  b8_t h1 = ((const b8_t*)(hin + base))[1];
  #pragma unroll
  for (int v=0;v<4;v++){
    f4_t a4 = Ap[v];
    #pragma unroll
    for (int k=0;k<4;k++){
      An2[v*4+k] = -__expf(a4[k])*LOG2E;
      int idx = v*4+k;
      h[idx] = (idx<8) ? (float)h0[idx] : (float)h1[idx-8];
    }
  }
  float Dv = Dp[ch];
  bf16_t* yp = ybf + (size_t)t0*DI + ch;
  #pragma unroll
  for (int l=0;l<CHUNK;l++){
    float de = (float)des[l][tid];
    float zv = (float)zs[l][tid];
    float xv = (float)xs[l][tid];
    float dx = de*xv;
    float y = 0.f;
    #pragma unroll
    for (int n=0;n<DS;n++){
      float dA = exp2f(de*An2[n]);
      h[n] = dA*h[n] + dx*Bs[l][n];
      y += h[n]*Cs[l][n];
    }
    y = (y + Dv*xv) * (zv * sigmoidf_(zv));
    yp[(size_t)l*DI] = (bf16_t)y;
  }
}

// ---------- head ----------
__global__ __launch_bounds__(256) void k_head(const float* __restrict__ h, const float* __restrict__ hw,
                                              const float* __restrict__ hb, float* __restrict__ out){
  int wave = threadIdx.x>>6, lane = threadIdx.x&63;
  int gw = blockIdx.x*4 + wave;                    // < B_*HOR
  int b = gw / HOR, hh = gw % HOR;
  const float* hp = h + ((size_t)b*L_ + (L_-1))*DM;
  const float* wp = hw + (size_t)hh*DM;
  float s = 0.f;
  #pragma unroll
  for (int k=0;k<DM;k+=64) s += hp[k+lane]*wp[k+lane];
  #pragma unroll
  for (int m=32;m;m>>=1) s += __shfl_xor(s, m);
  if (lane==0) out[gw] = s + hb[hh];
}

extern "C" void kernel_launch(void* const* d_in, const int* in_sizes, int n_in,
                              void* d_out, int out_size, void* d_ws, size_t ws_size,
                              hipStream_t stream){
  const float* x    = (const float*)d_in[0];
  const float* ew   = (const float*)d_in[1];
  const float* eb   = (const float*)d_in[2];
  const float* nw   = (const float*)d_in[3];
  const float* ipw  = (const float*)d_in[4];
  const float* cw   = (const float*)d_in[5];
  const float* cb   = (const float*)d_in[6];
  const float* xpw  = (const float*)d_in[7];
  const float* dtw  = (const float*)d_in[8];
  const float* dtb  = (const float*)d_in[9];
  const float* alog = (const float*)d_in[10];
  const float* Dp   = (const float*)d_in[11];
  const float* opw  = (const float*)d_in[12];
  const float* hw   = (const float*)d_in[13];
  const float* hb   = (const float*)d_in[14];
  float* out = (float*)d_out;

  char* ws = (char*)d_ws;
  size_t o = 0;
  float*  h      = (float*)(ws + o);  o += (size_t)8<<20;    // B*L*DM f32
  bf16_t* xzbf   = (bf16_t*)(ws + o); o += (size_t)16<<20;   // B*L*2DI bf16
  bf16_t* xinbf  = (bf16_t*)(ws + o); o += (size_t)8<<20;
  bf16_t* delta  = (bf16_t*)(ws + o); o += (size_t)8<<20;    // B*L*DI bf16
  bf16_t* ybf    = (bf16_t*)(ws + o); o += (size_t)8<<20;
  float*  dbc    = (float*)(ws + o);  o += (size_t)1<<20;    // only cols 32..63 used
  float*  dbcp   = (float*)(ws + o);  o += (size_t)8<<20;    // 8 split-K partials
  bf16_t* w_in   = (bf16_t*)(ws + o); o += (size_t)8<<20;
  bf16_t* w_out  = (bf16_t*)(ws + o); o += (size_t)4<<20;
  bf16_t* w_xp   = (bf16_t*)(ws + o); o += (size_t)1<<19;
  bf16_t* w_dt   = (bf16_t*)(ws + o); o += (size_t)1<<18;
  bf16_t* hend   = (bf16_t*)(ws + o); o += (size_t)8<<20;    // NCHK*B*DI*DS bf16
  bf16_t* aphin  = (bf16_t*)(ws + o); o += (size_t)8<<20;
  float*  sumsq  = (float*)(ws + o);  o += (size_t)(NL+1)*B_*L_*4;  // 5 x 16KB

  hipMemsetAsync(sumsq, 0, (NL+1)*B_*L_*4, stream);
  k_cvtall<<<6528,256,0,stream>>>(ipw, w_in, xpw, w_xp, dtw, w_dt, opw, w_out);
  k_embed<<<(B_*L_*DM)/256,256,0,stream>>>(x, ew, eb, h, sumsq);

  for (int i=0;i<NL;i++){
    // xz(bf16) = rmsnorm(h) @ in_proj^T   (M=4096,N=2048,K=512) -- 1024 blocks, rms fused
    k_gin<<<dim3(2*DI/128, B_*L_/64),256,0,stream>>>(h, sumsq + i*B_*L_, nw + i*DM,
                                                     w_in + (size_t)i*2*DI*DM, xzbf);
    // dbc partials = silu(conv(xz)) @ x_proj^T  (split-K x8, conv fused, xinbf emitted) -- 512 blocks
    k_dbc<<<dim3(B_*L_/64, 8),256,0,stream>>>(xzbf, cw + i*DI*DC, cb + i*DI,
                                              w_xp + (size_t)i*64*DI, dbcp, xinbf);
    // delta(bf16) = softplus(sum(partials)[:, :32] @ dt_w^T + dt_b); dbc B/C by n-block 0
    k_dt<<<dim3(DI/64, B_*L_/64),256,0,stream>>>(dbcp, w_dt + (size_t)i*DI*DTR,
                                                 dtb + i*DI, dbc, delta);
    // chunked selective scan (3-phase, LDS-staged, CHUNK=16)
    k_scan_p1<<<B_*NCHK*4,256,0,stream>>>(delta, xinbf, dbc, alog + i*DI*DS, hend, aphin);
    k_scan_p2<<<(B_*DI*DS)/256,256,0,stream>>>(hend, aphin);
    k_scan_p3<<<B_*NCHK*4,256,0,stream>>>(delta, xzbf, xinbf, dbc, alog + i*DI*DS,
                                          aphin, Dp + i*DI, ybf);
    // h += y @ out_proj^T (M=4096,N=512,K=1024) -- 512 blocks; emits sumsq for next layer
    k_gout<<<dim3(DM/64, B_*L_/64),256,0,stream>>>(ybf, w_out + (size_t)i*DM*DI,
                                                   h, sumsq + (i+1)*B_*L_);
  }
  k_head<<<(B_*HOR)/4,256,0,stream>>>(h, hw, hb, out);
}

// Round 12
// 626.252 us; speedup vs baseline: 1.0345x; 1.0345x over previous
//
#include <hip/hip_runtime.h>
#include <hip/hip_bf16.h>

#define B_  8
#define L_  512
#define DM  512
#define NL  4
#define DS  16
#define HOR 96
#define DC  4
#define DI  1024
#define DTR 32

#define CHUNK 16
#define NCHK (L_/CHUNK)   // 32

typedef __bf16 bf16_t;
typedef __bf16 b8_t __attribute__((ext_vector_type(8)));
typedef float  f4_t __attribute__((ext_vector_type(4)));

#define LOG2E 1.44269504088896f

__device__ __forceinline__ float sigmoidf_(float x){ return 1.f/(1.f+__expf(-x)); }

__device__ __forceinline__ void async16(const bf16_t* g, bf16_t* l){
  __builtin_amdgcn_global_load_lds((const __attribute__((address_space(1))) void*)g,
                                   (__attribute__((address_space(3))) void*)l, 16, 0, 0);
}

// ---------- fused f32 -> bf16 weight convert ----------
__global__ __launch_bounds__(256) void k_cvtall(const float* __restrict__ p0, bf16_t* __restrict__ o0,
                                                const float* __restrict__ p1, bf16_t* __restrict__ o1,
                                                const float* __restrict__ p2, bf16_t* __restrict__ o2,
                                                const float* __restrict__ p3, bf16_t* __restrict__ o3){
  int j = blockIdx.x*256 + threadIdx.x;   // v4 index
  const int S0=1048576, S1=65536, S2=32768;
  const float* src; bf16_t* dst;
  if (j < S0){ src=p0; dst=o0; }
  else if ((j-=S0) < S1){ src=p1; dst=o1; }
  else if ((j-=S1) < S2){ src=p2; dst=o2; }
  else { j-=S2; src=p3; dst=o3; }
  f4_t v = ((const f4_t*)src)[j];
  bf16_t* o = dst + (size_t)j*4;
  o[0]=(bf16_t)v[0]; o[1]=(bf16_t)v[1]; o[2]=(bf16_t)v[2]; o[3]=(bf16_t)v[3];
}

// ---------- embed ----------
__global__ __launch_bounds__(256) void k_embed(const float* __restrict__ x, const float* __restrict__ ew,
                                               const float* __restrict__ eb, float* __restrict__ h){
  int idx = blockIdx.x*256 + threadIdx.x;   // B*L*DM
  int d = idx & (DM-1); int t = idx >> 9;
  h[idx] = x[t]*ew[d] + eb[d];
}

// ---------- rmsnorm (fp32 in, bf16 out) ----------
__global__ __launch_bounds__(256) void k_rms(const float* __restrict__ h, const float* __restrict__ w,
                                             bf16_t* __restrict__ o){
  int t = blockIdx.x; int tid = threadIdx.x;
  const float* hp = h + (size_t)t*DM;
  float v0 = hp[tid], v1 = hp[tid+256];
  float s = v0*v0 + v1*v1;
  #pragma unroll
  for (int m=32;m;m>>=1) s += __shfl_xor(s, m);
  __shared__ float red[4];
  if ((tid&63)==0) red[tid>>6]=s;
  __syncthreads();
  float tot = red[0]+red[1]+red[2]+red[3];
  float sc = rsqrtf(tot*(1.f/DM) + 1e-5f);
  o[(size_t)t*DM + tid]       = (bf16_t)(v0*sc*w[tid]);
  o[(size_t)t*DM + tid + 256] = (bf16_t)(v1*sc*w[tid+256]);
}

// ---------- m97-structure 128x128 GEMM (in_proj): Cbf[M,N] = A[M,K] @ W[N,K]^T, bf16 out ----------
// 4 waves x 4x4 16x16x32 frags; 16 MFMA per barrier pair.
__global__ __launch_bounds__(256) void k_g128(const bf16_t* __restrict__ A, int lda,
                                              const bf16_t* __restrict__ W, int ldw,
                                              int K, bf16_t* __restrict__ Cbf, int ldc){
  __shared__ bf16_t As[128*32];
  __shared__ bf16_t Ws[128*32];
  int tid = threadIdx.x;
  int m0 = blockIdx.y*128, n0 = blockIdx.x*128;
  int wave = tid>>6, lane = tid&63;
  int wm = (wave>>1)*64, wn = (wave&1)*64;
  int lr = lane&15, q = lane>>4;
  int e0 = tid*8, r0 = e0>>5, c0 = e0&31;
  f4_t acc[4][4] = {};
  for (int k0=0;k0<K;k0+=32){
    async16(A + (size_t)(m0+r0)*lda + k0 + c0,    As + e0);
    async16(A + (size_t)(m0+r0+64)*lda + k0 + c0, As + e0 + 2048);
    async16(W + (size_t)(n0+r0)*ldw + k0 + c0,    Ws + e0);
    async16(W + (size_t)(n0+r0+64)*ldw + k0 + c0, Ws + e0 + 2048);
    __syncthreads();
    b8_t a[4], b[4];
    #pragma unroll
    for (int i=0;i<4;i++) a[i] = *(const b8_t*)(As + (wm+i*16+lr)*32 + q*8);
    #pragma unroll
    for (int j=0;j<4;j++) b[j] = *(const b8_t*)(Ws + (wn+j*16+lr)*32 + q*8);
    #pragma unroll
    for (int i=0;i<4;i++)
      #pragma unroll
      for (int j=0;j<4;j++)
        acc[i][j] = __builtin_amdgcn_mfma_f32_16x16x32_bf16(a[i], b[j], acc[i][j], 0,0,0);
    __syncthreads();
  }
  #pragma unroll
  for (int i=0;i<4;i++)
  #pragma unroll
  for (int j=0;j<4;j++){
    int col = n0 + wn + j*16 + lr;
    int rb  = m0 + wm + i*16 + q*4;
    #pragma unroll
    for (int r=0;r<4;r++)
      Cbf[(size_t)(rb+r)*ldc + col] = (bf16_t)acc[i][j][r];
  }
}

// ---------- out_proj GEMM: h += y @ Wo^T ; 64x64 tile, BK=64 (two 32-col panels) ----------
__global__ __launch_bounds__(256) void k_gout64(const bf16_t* __restrict__ A,
                                                const bf16_t* __restrict__ W,
                                                float* __restrict__ C){
  __shared__ bf16_t As[2*64*32];
  __shared__ bf16_t Ws[2*64*32];
  int tid = threadIdx.x;
  int m0 = blockIdx.y*64, n0 = blockIdx.x*64;
  int wave = tid>>6, lane = tid&63;
  int wm = (wave>>1)*32, wn = (wave&1)*32;
  int lr = lane&15, q = lane>>4;
  int e0 = tid*8, r0 = e0>>5, c0 = e0&31;
  f4_t acc[2][2] = {};
  for (int k0=0;k0<DI;k0+=64){
    async16(A + (size_t)(m0+r0)*DI + k0 + c0,      As + e0);
    async16(A + (size_t)(m0+r0)*DI + k0 + 32 + c0, As + e0 + 2048);
    async16(W + (size_t)(n0+r0)*DI + k0 + c0,      Ws + e0);
    async16(W + (size_t)(n0+r0)*DI + k0 + 32 + c0, Ws + e0 + 2048);
    __syncthreads();
    #pragma unroll
    for (int half=0;half<2;half++){
      b8_t a[2], b[2];
      #pragma unroll
      for (int i=0;i<2;i++) a[i] = *(const b8_t*)(As + half*2048 + (wm+i*16+lr)*32 + q*8);
      #pragma unroll
      for (int j=0;j<2;j++) b[j] = *(const b8_t*)(Ws + half*2048 + (wn+j*16+lr)*32 + q*8);
      #pragma unroll
      for (int i=0;i<2;i++)
        #pragma unroll
        for (int j=0;j<2;j++)
          acc[i][j] = __builtin_amdgcn_mfma_f32_16x16x32_bf16(a[i], b[j], acc[i][j], 0,0,0);
    }
    __syncthreads();
  }
  #pragma unroll
  for (int i=0;i<2;i++)
  #pragma unroll
  for (int j=0;j<2;j++){
    int col = n0 + wn + j*16 + lr;
    int rb  = m0 + wm + i*16 + q*4;
    #pragma unroll
    for (int r=0;r<4;r++){
      size_t off = (size_t)(rb+r)*DM + col;
      C[off] = C[off] + acc[i][j][r];
    }
  }
}

// ---------- x_proj GEMM with conv+silu fused into A staging (split-K x4); also emits xinbf ----------
__global__ __launch_bounds__(256) void k_dbc(const bf16_t* __restrict__ xzbf, const float* __restrict__ cw,
                                             const float* __restrict__ cb, const bf16_t* __restrict__ wxp,
                                             float* __restrict__ part, bf16_t* __restrict__ xinbf){
  __shared__ bf16_t As[64*32];
  __shared__ bf16_t Ws[64*32];
  int tid = threadIdx.x;
  int m0 = blockIdx.x*64;
  int z = blockIdx.y;
  int kbase = z*256;
  int wave = tid>>6, lane = tid&63;
  int wm = (wave>>1)*32, wn = (wave&1)*32;
  int lr = lane&15, q = lane>>4;
  int e0 = tid*8, r0 = e0>>5, c0 = e0&31;
  int gt = m0 + r0;              // global token
  int l  = gt & (L_-1);          // position within batch
  f4_t acc[2][2] = {};
  for (int k0=0;k0<256;k0+=32){
    int ch = kbase + k0 + c0;    // 8 channels ch..ch+7
    float cv[8];
    #pragma unroll
    for (int c=0;c<8;c++) cv[c] = cb[ch+c];
    #pragma unroll
    for (int k=0;k<DC;k++){
      if (l + k - (DC-1) >= 0){
        b8_t xv = *(const b8_t*)(xzbf + (size_t)(gt + k - (DC-1))*(2*DI) + ch);
        #pragma unroll
        for (int c=0;c<8;c++) cv[c] += (float)xv[c] * cw[(ch+c)*DC + k];
      }
    }
    b8_t av;
    #pragma unroll
    for (int c=0;c<8;c++){ float s = cv[c]*sigmoidf_(cv[c]); av[c] = (bf16_t)s; }
    *(b8_t*)(As + e0) = av;
    *(b8_t*)(xinbf + (size_t)gt*DI + ch) = av;     // each (token,channel) written once
    async16(wxp + (size_t)r0*DI + kbase + k0 + c0, Ws + e0);
    __syncthreads();
    b8_t a[2], b[2];
    #pragma unroll
    for (int i=0;i<2;i++) a[i] = *(const b8_t*)(As + (wm+i*16+lr)*32 + q*8);
    #pragma unroll
    for (int j=0;j<2;j++) b[j] = *(const b8_t*)(Ws + (wn+j*16+lr)*32 + q*8);
    #pragma unroll
    for (int i=0;i<2;i++)
      #pragma unroll
      for (int j=0;j<2;j++)
        acc[i][j] = __builtin_amdgcn_mfma_f32_16x16x32_bf16(a[i], b[j], acc[i][j], 0,0,0);
    __syncthreads();
  }
  float* P = part + (size_t)z*(B_*L_*64);
  #pragma unroll
  for (int i=0;i<2;i++)
  #pragma unroll
  for (int j=0;j<2;j++){
    int col = wn + j*16 + lr;
    int rb  = m0 + wm + i*16 + q*4;
    #pragma unroll
    for (int r=0;r<4;r++) P[(size_t)(rb+r)*64 + col] = acc[i][j][r];
  }
}

// ---------- fused: partial-reduce + dt-proj + softplus -> delta bf16; n-block0 writes dbc B/C f32 ----------
__global__ __launch_bounds__(256) void k_dt(const float* __restrict__ part, const bf16_t* __restrict__ wdt,
                                            const float* __restrict__ dtb, float* __restrict__ dbc,
                                            bf16_t* __restrict__ delta){
  __shared__ bf16_t As[64*32];
  __shared__ bf16_t Ws[64*32];
  int tid = threadIdx.x;
  int m0 = blockIdx.y*64, n0 = blockIdx.x*64;
  const size_t S = (size_t)B_*L_*64;
  int r0 = tid>>2, c0 = (tid&3)*8;
  int gt = m0 + r0;
  size_t base = (size_t)gt*64 + c0;
  f4_t s0 = *(const f4_t*)(part + base);
  f4_t s1 = *(const f4_t*)(part + base + 4);
  #pragma unroll
  for (int z=1;z<4;z++){
    s0 += *(const f4_t*)(part + z*S + base);
    s1 += *(const f4_t*)(part + z*S + base + 4);
  }
  b8_t av;
  #pragma unroll
  for (int c=0;c<4;c++){ av[c] = (bf16_t)s0[c]; av[4+c] = (bf16_t)s1[c]; }
  *(b8_t*)(As + tid*8) = av;
  if (n0 == 0){   // reduce + store B/C columns (32..64) in f32
    f4_t t0 = *(const f4_t*)(part + base + 32);
    f4_t t1 = *(const f4_t*)(part + base + 36);
    #pragma unroll
    for (int z=1;z<4;z++){
      t0 += *(const f4_t*)(part + z*S + base + 32);
      t1 += *(const f4_t*)(part + z*S + base + 36);
    }
    *(f4_t*)(dbc + base + 32) = t0;
    *(f4_t*)(dbc + base + 36) = t1;
  }
  async16(wdt + (size_t)(n0+r0)*DTR + c0, Ws + tid*8);
  __syncthreads();
  int wave = tid>>6, lane = tid&63;
  int wm = (wave>>1)*32, wn = (wave&1)*32;
  int lr = lane&15, q = lane>>4;
  b8_t a[2], b[2];
  #pragma unroll
  for (int i=0;i<2;i++) a[i] = *(const b8_t*)(As + (wm+i*16+lr)*32 + q*8);
  #pragma unroll
  for (int j=0;j<2;j++) b[j] = *(const b8_t*)(Ws + (wn+j*16+lr)*32 + q*8);
  f4_t acc[2][2] = {};
  #pragma unroll
  for (int i=0;i<2;i++)
    #pragma unroll
    for (int j=0;j<2;j++)
      acc[i][j] = __builtin_amdgcn_mfma_f32_16x16x32_bf16(a[i], b[j], acc[i][j], 0,0,0);
  #pragma unroll
  for (int i=0;i<2;i++)
  #pragma unroll
  for (int j=0;j<2;j++){
    int col = n0 + wn + j*16 + lr;
    int rb  = m0 + wm + i*16 + q*4;
    #pragma unroll
    for (int r=0;r<4;r++){
      float xv = acc[i][j][r] + dtb[col];
      float v = (xv>20.f)?xv:log1pf(__expf(xv));
      delta[(size_t)(rb+r)*DI + col] = (bf16_t)v;
    }
  }
}

// ---------- scan phase 1: LDS-staged chunk-local scan (h_in=0); bf16 state out ----------
__global__ __launch_bounds__(256) void k_scan_p1(const bf16_t* __restrict__ delta, const bf16_t* __restrict__ xin,
                                                 const float* __restrict__ dbc, const float* __restrict__ Alog,
                                                 bf16_t* __restrict__ hend, bf16_t* __restrict__ aprod){
  __shared__ bf16_t des[CHUNK][256];
  __shared__ bf16_t xs[CHUNK][256];
  __shared__ float Bs[CHUNK][DS];
  int tid = threadIdx.x;
  int blk = blockIdx.x;
  int chgrp = blk & 3;
  int chunk = (blk>>2) & (NCHK-1);
  int b = blk >> 7;
  int ch0 = chgrp<<8;
  int ch = ch0 + tid;
  int t0 = (b<<9) + chunk*CHUNK;
  #pragma unroll
  for (int idx=tid; idx<CHUNK*32; idx+=256){
    int row = idx>>5, c = (idx&31)*8;
    *(b8_t*)(&des[row][c]) = *(const b8_t*)(delta + (size_t)(t0+row)*DI + ch0 + c);
    *(b8_t*)(&xs[row][c])  = *(const b8_t*)(xin   + (size_t)(t0+row)*DI + ch0 + c);
  }
  {
    int ll = tid>>4, n = tid&15;
    Bs[ll][n] = dbc[(t0+ll)*64 + DTR + n];
  }
  __syncthreads();
  float An2[DS], h[DS];
  const f4_t* Ap = (const f4_t*)(Alog + ch*DS);
  #pragma unroll
  for (int v=0;v<4;v++){
    f4_t a4 = Ap[v];
    #pragma unroll
    for (int k=0;k<4;k++){ An2[v*4+k] = -__expf(a4[k])*LOG2E; h[v*4+k]=0.f; }
  }
  float sde = 0.f;
  #pragma unroll
  for (int l=0;l<CHUNK;l++){
    float de = (float)des[l][tid];
    float xv = (float)xs[l][tid];
    float dx = de*xv;
    sde += de;
    #pragma unroll
    for (int n=0;n<DS;n++){
      float dA = exp2f(de*An2[n]);
      h[n] = dA*h[n] + dx*Bs[l][n];
    }
  }
  size_t base = ((size_t)chunk*(B_*DI) + (b<<10) + ch)*DS;
  b8_t hv[2], av[2];
  #pragma unroll
  for (int v=0;v<2;v++)
    #pragma unroll
    for (int k=0;k<8;k++){
      hv[v][k] = (bf16_t)h[v*8+k];
      av[v][k] = (bf16_t)exp2f(An2[v*8+k]*sde);
    }
  ((b8_t*)(hend + base))[0] = hv[0]; ((b8_t*)(hend + base))[1] = hv[1];
  ((b8_t*)(aprod + base))[0] = av[0]; ((b8_t*)(aprod + base))[1] = av[1];
}

// ---------- scan phase 2: combine chunk transitions (bf16 in, bf16 hin out into aprod) ----------
__global__ __launch_bounds__(256) void k_scan_p2(const bf16_t* __restrict__ hend, bf16_t* __restrict__ ap_hin){
  int g = blockIdx.x*256 + threadIdx.x;   // B_*DI*DS
  float h = 0.f;
  for (int c=0;c<NCHK;c++){
    size_t off = (size_t)c*(B_*DI*DS) + g;
    float a = (float)ap_hin[off];
    float e = (float)hend[off];
    ap_hin[off] = (bf16_t)h;
    h = a*h + e;
  }
}

// ---------- scan phase 3: LDS-staged rerun with h_in, produce gated y (bf16) ----------
__global__ __launch_bounds__(256) void k_scan_p3(const bf16_t* __restrict__ delta, const bf16_t* __restrict__ xz,
                                                 const bf16_t* __restrict__ xin,
                                                 const float* __restrict__ dbc, const float* __restrict__ Alog,
                                                 const bf16_t* __restrict__ hin, const float* __restrict__ Dp,
                                                 bf16_t* __restrict__ ybf){
  __shared__ bf16_t des[CHUNK][256];
  __shared__ bf16_t xs[CHUNK][256];
  __shared__ bf16_t zs[CHUNK][256];
  __shared__ float Bs[CHUNK][DS];
  __shared__ float Cs[CHUNK][DS];
  int tid = threadIdx.x;
  int blk = blockIdx.x;
  int chgrp = blk & 3;
  int chunk = (blk>>2) & (NCHK-1);
  int b = blk >> 7;
  int ch0 = chgrp<<8;
  int ch = ch0 + tid;
  int t0 = (b<<9) + chunk*CHUNK;
  #pragma unroll
  for (int idx=tid; idx<CHUNK*32; idx+=256){
    int row = idx>>5, c = (idx&31)*8;
    *(b8_t*)(&des[row][c]) = *(const b8_t*)(delta + (size_t)(t0+row)*DI + ch0 + c);
    *(b8_t*)(&xs[row][c])  = *(const b8_t*)(xin   + (size_t)(t0+row)*DI + ch0 + c);
    *(b8_t*)(&zs[row][c])  = *(const b8_t*)(xz + (size_t)(t0+row)*(2*DI) + DI + ch0 + c);
  }
  {
    int ll = tid>>4, n = tid&15;
    Bs[ll][n] = dbc[(t0+ll)*64 + DTR + n];
    Cs[ll][n] = dbc[(t0+ll)*64 + DTR + DS + n];
  }
  __syncthreads();
  float An2[DS], h[DS];
  const f4_t* Ap = (const f4_t*)(Alog + ch*DS);
  size_t base = ((size_t)chunk*(B_*DI) + (b<<10) + ch)*DS;
  b8_t h0 = ((const b8_t*)(hin + base))[0];
  b8_t h1 = ((const b8_t*)(hin + base))[1];
  #pragma unroll
  for (int v=0;v<4;v++){
    f4_t a4 = Ap[v];
    #pragma unroll
    for (int k=0;k<4;k++){
      An2[v*4+k] = -__expf(a4[k])*LOG2E;
      int idx = v*4+k;
      h[idx] = (idx<8) ? (float)h0[idx] : (float)h1[idx-8];
    }
  }
  float Dv = Dp[ch];
  bf16_t* yp = ybf + (size_t)t0*DI + ch;
  #pragma unroll
  for (int l=0;l<CHUNK;l++){
    float de = (float)des[l][tid];
    float zv = (float)zs[l][tid];
    float xv = (float)xs[l][tid];
    float dx = de*xv;
    float y = 0.f;
    #pragma unroll
    for (int n=0;n<DS;n++){
      float dA = exp2f(de*An2[n]);
      h[n] = dA*h[n] + dx*Bs[l][n];
      y += h[n]*Cs[l][n];
    }
    y = (y + Dv*xv) * (zv * sigmoidf_(zv));
    yp[(size_t)l*DI] = (bf16_t)y;
  }
}

// ---------- head ----------
__global__ __launch_bounds__(256) void k_head(const float* __restrict__ h, const float* __restrict__ hw,
                                              const float* __restrict__ hb, float* __restrict__ out){
  int wave = threadIdx.x>>6, lane = threadIdx.x&63;
  int gw = blockIdx.x*4 + wave;                    // < B_*HOR
  int b = gw / HOR, hh = gw % HOR;
  const float* hp = h + ((size_t)b*L_ + (L_-1))*DM;
  const float* wp = hw + (size_t)hh*DM;
  float s = 0.f;
  #pragma unroll
  for (int k=0;k<DM;k+=64) s += hp[k+lane]*wp[k+lane];
  #pragma unroll
  for (int m=32;m;m>>=1) s += __shfl_xor(s, m);
  if (lane==0) out[gw] = s + hb[hh];
}

extern "C" void kernel_launch(void* const* d_in, const int* in_sizes, int n_in,
                              void* d_out, int out_size, void* d_ws, size_t ws_size,
                              hipStream_t stream){
  const float* x    = (const float*)d_in[0];
  const float* ew   = (const float*)d_in[1];
  const float* eb   = (const float*)d_in[2];
  const float* nw   = (const float*)d_in[3];
  const float* ipw  = (const float*)d_in[4];
  const float* cw   = (const float*)d_in[5];
  const float* cb   = (const float*)d_in[6];
  const float* xpw  = (const float*)d_in[7];
  const float* dtw  = (const float*)d_in[8];
  const float* dtb  = (const float*)d_in[9];
  const float* alog = (const float*)d_in[10];
  const float* Dp   = (const float*)d_in[11];
  const float* opw  = (const float*)d_in[12];
  const float* hw   = (const float*)d_in[13];
  const float* hb   = (const float*)d_in[14];
  float* out = (float*)d_out;

  char* ws = (char*)d_ws;
  size_t o = 0;
  float*  h      = (float*)(ws + o);  o += (size_t)8<<20;    // B*L*DM f32
  bf16_t* hnorm  = (bf16_t*)(ws + o); o += (size_t)4<<20;
  bf16_t* xzbf   = (bf16_t*)(ws + o); o += (size_t)16<<20;   // B*L*2DI bf16
  bf16_t* xinbf  = (bf16_t*)(ws + o); o += (size_t)8<<20;
  bf16_t* delta  = (bf16_t*)(ws + o); o += (size_t)8<<20;    // B*L*DI bf16
  bf16_t* ybf    = (bf16_t*)(ws + o); o += (size_t)8<<20;
  float*  dbc    = (float*)(ws + o);  o += (size_t)1<<20;    // only cols 32..63 used
  float*  dbcp   = (float*)(ws + o);  o += (size_t)4<<20;    // 4 split-K partials
  bf16_t* w_in   = (bf16_t*)(ws + o); o += (size_t)8<<20;
  bf16_t* w_out  = (bf16_t*)(ws + o); o += (size_t)4<<20;
  bf16_t* w_xp   = (bf16_t*)(ws + o); o += (size_t)1<<19;
  bf16_t* w_dt   = (bf16_t*)(ws + o); o += (size_t)1<<18;
  bf16_t* hend   = (bf16_t*)(ws + o); o += (size_t)8<<20;    // NCHK*B*DI*DS bf16
  bf16_t* aphin  = (bf16_t*)(ws + o); o += (size_t)8<<20;    // ~86 MB total

  k_cvtall<<<6528,256,0,stream>>>(ipw, w_in, xpw, w_xp, dtw, w_dt, opw, w_out);
  k_embed<<<(B_*L_*DM)/256,256,0,stream>>>(x, ew, eb, h);

  for (int i=0;i<NL;i++){
    k_rms<<<B_*L_,256,0,stream>>>(h, nw + i*DM, hnorm);
    // xz(bf16) = hnorm @ in_proj^T   (M=4096,N=2048,K=512) -- 512 blocks of 128x128
    k_g128<<<dim3(2*DI/128, B_*L_/128),256,0,stream>>>(
        hnorm, DM, w_in + (size_t)i*2*DI*DM, DM, DM, xzbf, 2*DI);
    // dbc partials = silu(conv(xz)) @ x_proj^T  (split-K x4, conv fused, xinbf emitted)
    k_dbc<<<dim3(B_*L_/64, 4),256,0,stream>>>(xzbf, cw + i*DI*DC, cb + i*DI,
                                              w_xp + (size_t)i*64*DI, dbcp, xinbf);
    // delta(bf16) = softplus(sum(partials)[:, :32] @ dt_w^T + dt_b); dbc B/C by n-block 0
    k_dt<<<dim3(DI/64, B_*L_/64),256,0,stream>>>(dbcp, w_dt + (size_t)i*DI*DTR,
                                                 dtb + i*DI, dbc, delta);
    // chunked selective scan (3-phase, LDS-staged, CHUNK=16)
    k_scan_p1<<<B_*NCHK*4,256,0,stream>>>(delta, xinbf, dbc, alog + i*DI*DS, hend, aphin);
    k_scan_p2<<<(B_*DI*DS)/256,256,0,stream>>>(hend, aphin);
    k_scan_p3<<<B_*NCHK*4,256,0,stream>>>(delta, xzbf, xinbf, dbc, alog + i*DI*DS,
                                          aphin, Dp + i*DI, ybf);
    // h += y @ out_proj^T (M=4096,N=512,K=1024) -- 512 blocks, BK=64
    k_gout64<<<dim3(DM/64, B_*L_/64),256,0,stream>>>(ybf, w_out + (size_t)i*DM*DI, h);
  }
  k_head<<<(B_*HOR)/4,256,0,stream>>>(h, hw, hb, out);
}

// Round 13
// 617.287 us; speedup vs baseline: 1.0496x; 1.0145x over previous
//
#include <hip/hip_runtime.h>
#include <hip/hip_bf16.h>

#define B_  8
#define L_  512
#define DM  512
#define NL  4
#define DS  16
#define HOR 96
#define DC  4
#define DI  1024
#define DTR 32

#define CHUNK 16
#define NCHK (L_/CHUNK)   // 32

typedef __bf16 bf16_t;
typedef __bf16 b8_t __attribute__((ext_vector_type(8)));
typedef float  f4_t __attribute__((ext_vector_type(4)));

#define LOG2E 1.44269504088896f

__device__ __forceinline__ float sigmoidf_(float x){ return 1.f/(1.f+__expf(-x)); }

__device__ __forceinline__ void async16(const bf16_t* g, bf16_t* l){
  __builtin_amdgcn_global_load_lds((const __attribute__((address_space(1))) void*)g,
                                   (__attribute__((address_space(3))) void*)l, 16, 0, 0);
}

// ---------- fused f32 -> bf16 weight convert ----------
__global__ __launch_bounds__(256) void k_cvtall(const float* __restrict__ p0, bf16_t* __restrict__ o0,
                                                const float* __restrict__ p1, bf16_t* __restrict__ o1,
                                                const float* __restrict__ p2, bf16_t* __restrict__ o2,
                                                const float* __restrict__ p3, bf16_t* __restrict__ o3){
  int j = blockIdx.x*256 + threadIdx.x;   // v4 index
  const int S0=1048576, S1=65536, S2=32768;
  const float* src; bf16_t* dst;
  if (j < S0){ src=p0; dst=o0; }
  else if ((j-=S0) < S1){ src=p1; dst=o1; }
  else if ((j-=S1) < S2){ src=p2; dst=o2; }
  else { j-=S2; src=p3; dst=o3; }
  f4_t v = ((const f4_t*)src)[j];
  bf16_t* o = dst + (size_t)j*4;
  o[0]=(bf16_t)v[0]; o[1]=(bf16_t)v[1]; o[2]=(bf16_t)v[2]; o[3]=(bf16_t)v[3];
}

// ---------- embed ----------
__global__ __launch_bounds__(256) void k_embed(const float* __restrict__ x, const float* __restrict__ ew,
                                               const float* __restrict__ eb, float* __restrict__ h){
  int idx = blockIdx.x*256 + threadIdx.x;   // B*L*DM
  int d = idx & (DM-1); int t = idx >> 9;
  h[idx] = x[t]*ew[d] + eb[d];
}

// ---------- rmsnorm (fp32 in, bf16 out) ----------
__global__ __launch_bounds__(256) void k_rms(const float* __restrict__ h, const float* __restrict__ w,
                                             bf16_t* __restrict__ o){
  int t = blockIdx.x; int tid = threadIdx.x;
  const float* hp = h + (size_t)t*DM;
  float v0 = hp[tid], v1 = hp[tid+256];
  float s = v0*v0 + v1*v1;
  #pragma unroll
  for (int m=32;m;m>>=1) s += __shfl_xor(s, m);
  __shared__ float red[4];
  if ((tid&63)==0) red[tid>>6]=s;
  __syncthreads();
  float tot = red[0]+red[1]+red[2]+red[3];
  float sc = rsqrtf(tot*(1.f/DM) + 1e-5f);
  o[(size_t)t*DM + tid]       = (bf16_t)(v0*sc*w[tid]);
  o[(size_t)t*DM + tid + 256] = (bf16_t)(v1*sc*w[tid+256]);
}

// ---------- 128x128 GEMM (in_proj), BK=64: 32 MFMA per barrier pair ----------
__global__ __launch_bounds__(256) void k_g128(const bf16_t* __restrict__ A, int lda,
                                              const bf16_t* __restrict__ W, int ldw,
                                              int K, bf16_t* __restrict__ Cbf, int ldc){
  __shared__ bf16_t As[2*128*32];
  __shared__ bf16_t Ws[2*128*32];
  int tid = threadIdx.x;
  int m0 = blockIdx.y*128, n0 = blockIdx.x*128;
  int wave = tid>>6, lane = tid&63;
  int wm = (wave>>1)*64, wn = (wave&1)*64;
  int lr = lane&15, q = lane>>4;
  int rs = tid>>2, cs = (tid&3)*8;       // staging row/col within a 32-col panel pass
  f4_t acc[4][4] = {};
  for (int k0=0;k0<K;k0+=64){
    #pragma unroll
    for (int p=0;p<2;p++){
      #pragma unroll
      for (int s=0;s<2;s++){
        int row = s*64 + rs;
        async16(A + (size_t)(m0+row)*lda + k0 + p*32 + cs, As + p*4096 + s*2048 + tid*8);
        async16(W + (size_t)(n0+row)*ldw + k0 + p*32 + cs, Ws + p*4096 + s*2048 + tid*8);
      }
    }
    __syncthreads();
    #pragma unroll
    for (int p=0;p<2;p++){
      b8_t a[4], b[4];
      #pragma unroll
      for (int i=0;i<4;i++) a[i] = *(const b8_t*)(As + p*4096 + (wm+i*16+lr)*32 + q*8);
      #pragma unroll
      for (int j=0;j<4;j++) b[j] = *(const b8_t*)(Ws + p*4096 + (wn+j*16+lr)*32 + q*8);
      #pragma unroll
      for (int i=0;i<4;i++)
        #pragma unroll
        for (int j=0;j<4;j++)
          acc[i][j] = __builtin_amdgcn_mfma_f32_16x16x32_bf16(a[i], b[j], acc[i][j], 0,0,0);
    }
    __syncthreads();
  }
  #pragma unroll
  for (int i=0;i<4;i++)
  #pragma unroll
  for (int j=0;j<4;j++){
    int col = n0 + wn + j*16 + lr;
    int rb  = m0 + wm + i*16 + q*4;
    #pragma unroll
    for (int r=0;r<4;r++)
      Cbf[(size_t)(rb+r)*ldc + col] = (bf16_t)acc[i][j][r];
  }
}

// ---------- out_proj GEMM: h += y @ Wo^T ; 64x64 tile, BK=64 ----------
__global__ __launch_bounds__(256) void k_gout64(const bf16_t* __restrict__ A,
                                                const bf16_t* __restrict__ W,
                                                float* __restrict__ C){
  __shared__ bf16_t As[2*64*32];
  __shared__ bf16_t Ws[2*64*32];
  int tid = threadIdx.x;
  int m0 = blockIdx.y*64, n0 = blockIdx.x*64;
  int wave = tid>>6, lane = tid&63;
  int wm = (wave>>1)*32, wn = (wave&1)*32;
  int lr = lane&15, q = lane>>4;
  int e0 = tid*8, r0 = e0>>5, c0 = e0&31;
  f4_t acc[2][2] = {};
  for (int k0=0;k0<DI;k0+=64){
    async16(A + (size_t)(m0+r0)*DI + k0 + c0,      As + e0);
    async16(A + (size_t)(m0+r0)*DI + k0 + 32 + c0, As + e0 + 2048);
    async16(W + (size_t)(n0+r0)*DI + k0 + c0,      Ws + e0);
    async16(W + (size_t)(n0+r0)*DI + k0 + 32 + c0, Ws + e0 + 2048);
    __syncthreads();
    #pragma unroll
    for (int half=0;half<2;half++){
      b8_t a[2], b[2];
      #pragma unroll
      for (int i=0;i<2;i++) a[i] = *(const b8_t*)(As + half*2048 + (wm+i*16+lr)*32 + q*8);
      #pragma unroll
      for (int j=0;j<2;j++) b[j] = *(const b8_t*)(Ws + half*2048 + (wn+j*16+lr)*32 + q*8);
      #pragma unroll
      for (int i=0;i<2;i++)
        #pragma unroll
        for (int j=0;j<2;j++)
          acc[i][j] = __builtin_amdgcn_mfma_f32_16x16x32_bf16(a[i], b[j], acc[i][j], 0,0,0);
    }
    __syncthreads();
  }
  #pragma unroll
  for (int i=0;i<2;i++)
  #pragma unroll
  for (int j=0;j<2;j++){
    int col = n0 + wn + j*16 + lr;
    int rb  = m0 + wm + i*16 + q*4;
    #pragma unroll
    for (int r=0;r<4;r++){
      size_t off = (size_t)(rb+r)*DM + col;
      C[off] = C[off] + acc[i][j][r];
    }
  }
}

// ---------- x_proj GEMM, BK=64 (two conv panels), split-K x4; emits xinbf ----------
__global__ __launch_bounds__(256) void k_dbc(const bf16_t* __restrict__ xzbf, const float* __restrict__ cw,
                                             const float* __restrict__ cb, const bf16_t* __restrict__ wxp,
                                             float* __restrict__ part, bf16_t* __restrict__ xinbf){
  __shared__ bf16_t As[2*64*32];
  __shared__ bf16_t Ws[2*64*32];
  int tid = threadIdx.x;
  int m0 = blockIdx.x*64;
  int z = blockIdx.y;
  int kbase = z*256;
  int wave = tid>>6, lane = tid&63;
  int wm = (wave>>1)*32, wn = (wave&1)*32;
  int lr = lane&15, q = lane>>4;
  int e0 = tid*8, r0 = e0>>5, c0 = e0&31;
  int gt = m0 + r0;              // global token
  int l  = gt & (L_-1);          // position within batch
  f4_t acc[2][2] = {};
  for (int k0=0;k0<256;k0+=64){
    #pragma unroll
    for (int p=0;p<2;p++){
      int ch = kbase + k0 + p*32 + c0;    // 8 channels
      float cv[8];
      #pragma unroll
      for (int c=0;c<8;c++) cv[c] = cb[ch+c];
      #pragma unroll
      for (int k=0;k<DC;k++){
        if (l + k - (DC-1) >= 0){
          b8_t xv = *(const b8_t*)(xzbf + (size_t)(gt + k - (DC-1))*(2*DI) + ch);
          #pragma unroll
          for (int c=0;c<8;c++) cv[c] += (float)xv[c] * cw[(ch+c)*DC + k];
        }
      }
      b8_t av;
      #pragma unroll
      for (int c=0;c<8;c++){ float s = cv[c]*sigmoidf_(cv[c]); av[c] = (bf16_t)s; }
      *(b8_t*)(As + p*2048 + e0) = av;
      *(b8_t*)(xinbf + (size_t)gt*DI + ch) = av;
      async16(wxp + (size_t)r0*DI + kbase + k0 + p*32 + c0, Ws + p*2048 + e0);
    }
    __syncthreads();
    #pragma unroll
    for (int p=0;p<2;p++){
      b8_t a[2], b[2];
      #pragma unroll
      for (int i=0;i<2;i++) a[i] = *(const b8_t*)(As + p*2048 + (wm+i*16+lr)*32 + q*8);
      #pragma unroll
      for (int j=0;j<2;j++) b[j] = *(const b8_t*)(Ws + p*2048 + (wn+j*16+lr)*32 + q*8);
      #pragma unroll
      for (int i=0;i<2;i++)
        #pragma unroll
        for (int j=0;j<2;j++)
          acc[i][j] = __builtin_amdgcn_mfma_f32_16x16x32_bf16(a[i], b[j], acc[i][j], 0,0,0);
    }
    __syncthreads();
  }
  float* P = part + (size_t)z*(B_*L_*64);
  #pragma unroll
  for (int i=0;i<2;i++)
  #pragma unroll
  for (int j=0;j<2;j++){
    int col = wn + j*16 + lr;
    int rb  = m0 + wm + i*16 + q*4;
    #pragma unroll
    for (int r=0;r<4;r++) P[(size_t)(rb+r)*64 + col] = acc[i][j][r];
  }
}

// ---------- fused: partial-reduce + dt-proj + softplus -> delta bf16; n-block0 writes dbc B/C f32 ----------
__global__ __launch_bounds__(256) void k_dt(const float* __restrict__ part, const bf16_t* __restrict__ wdt,
                                            const float* __restrict__ dtb, float* __restrict__ dbc,
                                            bf16_t* __restrict__ delta){
  __shared__ bf16_t As[64*32];
  __shared__ bf16_t Ws[64*32];
  int tid = threadIdx.x;
  int m0 = blockIdx.y*64, n0 = blockIdx.x*64;
  const size_t S = (size_t)B_*L_*64;
  int r0 = tid>>2, c0 = (tid&3)*8;
  int gt = m0 + r0;
  size_t base = (size_t)gt*64 + c0;
  f4_t s0 = *(const f4_t*)(part + base);
  f4_t s1 = *(const f4_t*)(part + base + 4);
  #pragma unroll
  for (int z=1;z<4;z++){
    s0 += *(const f4_t*)(part + z*S + base);
    s1 += *(const f4_t*)(part + z*S + base + 4);
  }
  b8_t av;
  #pragma unroll
  for (int c=0;c<4;c++){ av[c] = (bf16_t)s0[c]; av[4+c] = (bf16_t)s1[c]; }
  *(b8_t*)(As + tid*8) = av;
  if (n0 == 0){   // reduce + store B/C columns (32..64) in f32
    f4_t t0 = *(const f4_t*)(part + base + 32);
    f4_t t1 = *(const f4_t*)(part + base + 36);
    #pragma unroll
    for (int z=1;z<4;z++){
      t0 += *(const f4_t*)(part + z*S + base + 32);
      t1 += *(const f4_t*)(part + z*S + base + 36);
    }
    *(f4_t*)(dbc + base + 32) = t0;
    *(f4_t*)(dbc + base + 36) = t1;
  }
  async16(wdt + (size_t)(n0+r0)*DTR + c0, Ws + tid*8);
  __syncthreads();
  int wave = tid>>6, lane = tid&63;
  int wm = (wave>>1)*32, wn = (wave&1)*32;
  int lr = lane&15, q = lane>>4;
  b8_t a[2], b[2];
  #pragma unroll
  for (int i=0;i<2;i++) a[i] = *(const b8_t*)(As + (wm+i*16+lr)*32 + q*8);
  #pragma unroll
  for (int j=0;j<2;j++) b[j] = *(const b8_t*)(Ws + (wn+j*16+lr)*32 + q*8);
  f4_t acc[2][2] = {};
  #pragma unroll
  for (int i=0;i<2;i++)
    #pragma unroll
    for (int j=0;j<2;j++)
      acc[i][j] = __builtin_amdgcn_mfma_f32_16x16x32_bf16(a[i], b[j], acc[i][j], 0,0,0);
  #pragma unroll
  for (int i=0;i<2;i++)
  #pragma unroll
  for (int j=0;j<2;j++){
    int col = n0 + wn + j*16 + lr;
    int rb  = m0 + wm + i*16 + q*4;
    #pragma unroll
    for (int r=0;r<4;r++){
      float xv = acc[i][j][r] + dtb[col];
      float v = (xv>20.f)?xv:log1pf(__expf(xv));
      delta[(size_t)(rb+r)*DI + col] = (bf16_t)v;
    }
  }
}

// ---------- scan phase 1: LDS-staged chunk-local scan (h_in=0); bf16 state out ----------
__global__ __launch_bounds__(256) void k_scan_p1(const bf16_t* __restrict__ delta, const bf16_t* __restrict__ xin,
                                                 const float* __restrict__ dbc, const float* __restrict__ Alog,
                                                 bf16_t* __restrict__ hend, bf16_t* __restrict__ aprod){
  __shared__ bf16_t des[CHUNK][256];
  __shared__ bf16_t xs[CHUNK][256];
  __shared__ float Bs[CHUNK][DS];
  int tid = threadIdx.x;
  int blk = blockIdx.x;
  int chgrp = blk & 3;
  int chunk = (blk>>2) & (NCHK-1);
  int b = blk >> 7;
  int ch0 = chgrp<<8;
  int ch = ch0 + tid;
  int t0 = (b<<9) + chunk*CHUNK;
  #pragma unroll
  for (int idx=tid; idx<CHUNK*32; idx+=256){
    int row = idx>>5, c = (idx&31)*8;
    *(b8_t*)(&des[row][c]) = *(const b8_t*)(delta + (size_t)(t0+row)*DI + ch0 + c);
    *(b8_t*)(&xs[row][c])  = *(const b8_t*)(xin   + (size_t)(t0+row)*DI + ch0 + c);
  }
  {
    int ll = tid>>4, n = tid&15;
    Bs[ll][n] = dbc[(t0+ll)*64 + DTR + n];
  }
  __syncthreads();
  float An2[DS], h[DS];
  const f4_t* Ap = (const f4_t*)(Alog + ch*DS);
  #pragma unroll
  for (int v=0;v<4;v++){
    f4_t a4 = Ap[v];
    #pragma unroll
    for (int k=0;k<4;k++){ An2[v*4+k] = -__expf(a4[k])*LOG2E; h[v*4+k]=0.f; }
  }
  float sde = 0.f;
  #pragma unroll
  for (int l=0;l<CHUNK;l++){
    float de = (float)des[l][tid];
    float xv = (float)xs[l][tid];
    float dx = de*xv;
    sde += de;
    #pragma unroll
    for (int n=0;n<DS;n++){
      float dA = exp2f(de*An2[n]);
      h[n] = dA*h[n] + dx*Bs[l][n];
    }
  }
  size_t base = ((size_t)chunk*(B_*DI) + (b<<10) + ch)*DS;
  b8_t hv[2], av[2];
  #pragma unroll
  for (int v=0;v<2;v++)
    #pragma unroll
    for (int k=0;k<8;k++){
      hv[v][k] = (bf16_t)h[v*8+k];
      av[v][k] = (bf16_t)exp2f(An2[v*8+k]*sde);
    }
  ((b8_t*)(hend + base))[0] = hv[0]; ((b8_t*)(hend + base))[1] = hv[1];
  ((b8_t*)(aprod + base))[0] = av[0]; ((b8_t*)(aprod + base))[1] = av[1];
}

// ---------- scan phase 2: combine chunk transitions (bf16 in, bf16 hin out into aprod) ----------
__global__ __launch_bounds__(256) void k_scan_p2(const bf16_t* __restrict__ hend, bf16_t* __restrict__ ap_hin){
  int g = blockIdx.x*256 + threadIdx.x;   // B_*DI*DS
  float h = 0.f;
  for (int c=0;c<NCHK;c++){
    size_t off = (size_t)c*(B_*DI*DS) + g;
    float a = (float)ap_hin[off];
    float e = (float)hend[off];
    ap_hin[off] = (bf16_t)h;
    h = a*h + e;
  }
}

// ---------- scan phase 3: LDS-staged rerun with h_in, produce gated y (bf16) ----------
__global__ __launch_bounds__(256) void k_scan_p3(const bf16_t* __restrict__ delta, const bf16_t* __restrict__ xz,
                                                 const bf16_t* __restrict__ xin,
                                                 const float* __restrict__ dbc, const float* __restrict__ Alog,
                                                 const bf16_t* __restrict__ hin, const float* __restrict__ Dp,
                                                 bf16_t* __restrict__ ybf){
  __shared__ bf16_t des[CHUNK][256];
  __shared__ bf16_t xs[CHUNK][256];
  __shared__ bf16_t zs[CHUNK][256];
  __shared__ float Bs[CHUNK][DS];
  __shared__ float Cs[CHUNK][DS];
  int tid = threadIdx.x;
  int blk = blockIdx.x;
  int chgrp = blk & 3;
  int chunk = (blk>>2) & (NCHK-1);
  int b = blk >> 7;
  int ch0 = chgrp<<8;
  int ch = ch0 + tid;
  int t0 = (b<<9) + chunk*CHUNK;
  #pragma unroll
  for (int idx=tid; idx<CHUNK*32; idx+=256){
    int row = idx>>5, c = (idx&31)*8;
    *(b8_t*)(&des[row][c]) = *(const b8_t*)(delta + (size_t)(t0+row)*DI + ch0 + c);
    *(b8_t*)(&xs[row][c])  = *(const b8_t*)(xin   + (size_t)(t0+row)*DI + ch0 + c);
    *(b8_t*)(&zs[row][c])  = *(const b8_t*)(xz + (size_t)(t0+row)*(2*DI) + DI + ch0 + c);
  }
  {
    int ll = tid>>4, n = tid&15;
    Bs[ll][n] = dbc[(t0+ll)*64 + DTR + n];
    Cs[ll][n] = dbc[(t0+ll)*64 + DTR + DS + n];
  }
  __syncthreads();
  float An2[DS], h[DS];
  const f4_t* Ap = (const f4_t*)(Alog + ch*DS);
  size_t base = ((size_t)chunk*(B_*DI) + (b<<10) + ch)*DS;
  b8_t h0 = ((const b8_t*)(hin + base))[0];
  b8_t h1 = ((const b8_t*)(hin + base))[1];
  #pragma unroll
  for (int v=0;v<4;v++){
    f4_t a4 = Ap[v];
    #pragma unroll
    for (int k=0;k<4;k++){
      An2[v*4+k] = -__expf(a4[k])*LOG2E;
      int idx = v*4+k;
      h[idx] = (idx<8) ? (float)h0[idx] : (float)h1[idx-8];
    }
  }
  float Dv = Dp[ch];
  bf16_t* yp = ybf + (size_t)t0*DI + ch;
  #pragma unroll
  for (int l=0;l<CHUNK;l++){
    float de = (float)des[l][tid];
    float zv = (float)zs[l][tid];
    float xv = (float)xs[l][tid];
    float dx = de*xv;
    float y = 0.f;
    #pragma unroll
    for (int n=0;n<DS;n++){
      float dA = exp2f(de*An2[n]);
      h[n] = dA*h[n] + dx*Bs[l][n];
      y += h[n]*Cs[l][n];
    }
    y = (y + Dv*xv) * (zv * sigmoidf_(zv));
    yp[(size_t)l*DI] = (bf16_t)y;
  }
}

// ---------- head ----------
__global__ __launch_bounds__(256) void k_head(const float* __restrict__ h, const float* __restrict__ hw,
                                              const float* __restrict__ hb, float* __restrict__ out){
  int wave = threadIdx.x>>6, lane = threadIdx.x&63;
  int gw = blockIdx.x*4 + wave;                    // < B_*HOR
  int b = gw / HOR, hh = gw % HOR;
  const float* hp = h + ((size_t)b*L_ + (L_-1))*DM;
  const float* wp = hw + (size_t)hh*DM;
  float s = 0.f;
  #pragma unroll
  for (int k=0;k<DM;k+=64) s += hp[k+lane]*wp[k+lane];
  #pragma unroll
  for (int m=32;m;m>>=1) s += __shfl_xor(s, m);
  if (lane==0) out[gw] = s + hb[hh];
}

extern "C" void kernel_launch(void* const* d_in, const int* in_sizes, int n_in,
                              void* d_out, int out_size, void* d_ws, size_t ws_size,
                              hipStream_t stream){
  const float* x    = (const float*)d_in[0];
  const float* ew   = (const float*)d_in[1];
  const float* eb   = (const float*)d_in[2];
  const float* nw   = (const float*)d_in[3];
  const float* ipw  = (const float*)d_in[4];
  const float* cw   = (const float*)d_in[5];
  const float* cb   = (const float*)d_in[6];
  const float* xpw  = (const float*)d_in[7];
  const float* dtw  = (const float*)d_in[8];
  const float* dtb  = (const float*)d_in[9];
  const float* alog = (const float*)d_in[10];
  const float* Dp   = (const float*)d_in[11];
  const float* opw  = (const float*)d_in[12];
  const float* hw   = (const float*)d_in[13];
  const float* hb   = (const float*)d_in[14];
  float* out = (float*)d_out;

  char* ws = (char*)d_ws;
  size_t o = 0;
  float*  h      = (float*)(ws + o);  o += (size_t)8<<20;    // B*L*DM f32
  bf16_t* hnorm  = (bf16_t*)(ws + o); o += (size_t)4<<20;
  bf16_t* xzbf   = (bf16_t*)(ws + o); o += (size_t)16<<20;   // B*L*2DI bf16
  bf16_t* xinbf  = (bf16_t*)(ws + o); o += (size_t)8<<20;
  bf16_t* delta  = (bf16_t*)(ws + o); o += (size_t)8<<20;    // B*L*DI bf16
  bf16_t* ybf    = (bf16_t*)(ws + o); o += (size_t)8<<20;
  float*  dbc    = (float*)(ws + o);  o += (size_t)1<<20;    // only cols 32..63 used
  float*  dbcp   = (float*)(ws + o);  o += (size_t)4<<20;    // 4 split-K partials
  bf16_t* w_in   = (bf16_t*)(ws + o); o += (size_t)8<<20;
  bf16_t* w_out  = (bf16_t*)(ws + o); o += (size_t)4<<20;
  bf16_t* w_xp   = (bf16_t*)(ws + o); o += (size_t)1<<19;
  bf16_t* w_dt   = (bf16_t*)(ws + o); o += (size_t)1<<18;
  bf16_t* hend   = (bf16_t*)(ws + o); o += (size_t)8<<20;    // NCHK*B*DI*DS bf16
  bf16_t* aphin  = (bf16_t*)(ws + o); o += (size_t)8<<20;    // ~86 MB total

  k_cvtall<<<6528,256,0,stream>>>(ipw, w_in, xpw, w_xp, dtw, w_dt, opw, w_out);
  k_embed<<<(B_*L_*DM)/256,256,0,stream>>>(x, ew, eb, h);

  for (int i=0;i<NL;i++){
    k_rms<<<B_*L_,256,0,stream>>>(h, nw + i*DM, hnorm);
    // xz(bf16) = hnorm @ in_proj^T   (M=4096,N=2048,K=512) -- 512 blocks of 128x128, BK=64
    k_g128<<<dim3(2*DI/128, B_*L_/128),256,0,stream>>>(
        hnorm, DM, w_in + (size_t)i*2*DI*DM, DM, DM, xzbf, 2*DI);
    // dbc partials = silu(conv(xz)) @ x_proj^T  (split-K x4, BK=64, conv fused, xinbf emitted)
    k_dbc<<<dim3(B_*L_/64, 4),256,0,stream>>>(xzbf, cw + i*DI*DC, cb + i*DI,
                                              w_xp + (size_t)i*64*DI, dbcp, xinbf);
    // delta(bf16) = softplus(sum(partials)[:, :32] @ dt_w^T + dt_b); dbc B/C by n-block 0
    k_dt<<<dim3(DI/64, B_*L_/64),256,0,stream>>>(dbcp, w_dt + (size_t)i*DI*DTR,
                                                 dtb + i*DI, dbc, delta);
    // chunked selective scan (3-phase, LDS-staged, CHUNK=16)
    k_scan_p1<<<B_*NCHK*4,256,0,stream>>>(delta, xinbf, dbc, alog + i*DI*DS, hend, aphin);
    k_scan_p2<<<(B_*DI*DS)/256,256,0,stream>>>(hend, aphin);
    k_scan_p3<<<B_*NCHK*4,256,0,stream>>>(delta, xzbf, xinbf, dbc, alog + i*DI*DS,
                                          aphin, Dp + i*DI, ybf);
    // h += y @ out_proj^T (M=4096,N=512,K=1024) -- 512 blocks, BK=64
    k_gout64<<<dim3(DM/64, B_*L_/64),256,0,stream>>>(ybf, w_out + (size_t)i*DM*DI, h);
  }
  k_head<<<(B_*HOR)/4,256,0,stream>>>(h, hw, hb, out);
}

// Round 14
// 606.375 us; speedup vs baseline: 1.0685x; 1.0180x over previous
//
#include <hip/hip_runtime.h>
#include <hip/hip_bf16.h>

#define B_  8
#define L_  512
#define DM  512
#define NL  4
#define DS  16
#define HOR 96
#define DC  4
#define DI  1024
#define DTR 32

#define CHUNK 16
#define NCHK (L_/CHUNK)   // 32

typedef __bf16 bf16_t;
typedef __bf16 b8_t __attribute__((ext_vector_type(8)));
typedef float  f4_t __attribute__((ext_vector_type(4)));

#define LOG2E 1.44269504088896f

__device__ __forceinline__ float sigmoidf_(float x){ return 1.f/(1.f+__expf(-x)); }

__device__ __forceinline__ void async16(const bf16_t* g, bf16_t* l){
  __builtin_amdgcn_global_load_lds((const __attribute__((address_space(1))) void*)g,
                                   (__attribute__((address_space(3))) void*)l, 16, 0, 0);
}

// ---------- fused f32 -> bf16 weight convert ----------
__global__ __launch_bounds__(256) void k_cvtall(const float* __restrict__ p0, bf16_t* __restrict__ o0,
                                                const float* __restrict__ p1, bf16_t* __restrict__ o1,
                                                const float* __restrict__ p2, bf16_t* __restrict__ o2,
                                                const float* __restrict__ p3, bf16_t* __restrict__ o3){
  int j = blockIdx.x*256 + threadIdx.x;   // v4 index
  const int S0=1048576, S1=65536, S2=32768;
  const float* src; bf16_t* dst;
  if (j < S0){ src=p0; dst=o0; }
  else if ((j-=S0) < S1){ src=p1; dst=o1; }
  else if ((j-=S1) < S2){ src=p2; dst=o2; }
  else { j-=S2; src=p3; dst=o3; }
  f4_t v = ((const f4_t*)src)[j];
  bf16_t* o = dst + (size_t)j*4;
  o[0]=(bf16_t)v[0]; o[1]=(bf16_t)v[1]; o[2]=(bf16_t)v[2]; o[3]=(bf16_t)v[3];
}

// ---------- embed ----------
__global__ __launch_bounds__(256) void k_embed(const float* __restrict__ x, const float* __restrict__ ew,
                                               const float* __restrict__ eb, float* __restrict__ h){
  int idx = blockIdx.x*256 + threadIdx.x;   // B*L*DM
  int d = idx & (DM-1); int t = idx >> 9;
  h[idx] = x[t]*ew[d] + eb[d];
}

// ---------- rmsnorm (fp32 in, bf16 out) ----------
__global__ __launch_bounds__(256) void k_rms(const float* __restrict__ h, const float* __restrict__ w,
                                             bf16_t* __restrict__ o){
  int t = blockIdx.x; int tid = threadIdx.x;
  const float* hp = h + (size_t)t*DM;
  float v0 = hp[tid], v1 = hp[tid+256];
  float s = v0*v0 + v1*v1;
  #pragma unroll
  for (int m=32;m;m>>=1) s += __shfl_xor(s, m);
  __shared__ float red[4];
  if ((tid&63)==0) red[tid>>6]=s;
  __syncthreads();
  float tot = red[0]+red[1]+red[2]+red[3];
  float sc = rsqrtf(tot*(1.f/DM) + 1e-5f);
  o[(size_t)t*DM + tid]       = (bf16_t)(v0*sc*w[tid]);
  o[(size_t)t*DM + tid + 256] = (bf16_t)(v1*sc*w[tid+256]);
}

// ---------- 128x128 GEMM (in_proj), BK=128: 64 MFMA per barrier pair, 4 outer iters ----------
__global__ __launch_bounds__(256) void k_g128(const bf16_t* __restrict__ A, int lda,
                                              const bf16_t* __restrict__ W, int ldw,
                                              int K, bf16_t* __restrict__ Cbf, int ldc){
  __shared__ bf16_t As[4*128*32];
  __shared__ bf16_t Ws[4*128*32];
  int tid = threadIdx.x;
  int m0 = blockIdx.y*128, n0 = blockIdx.x*128;
  int wave = tid>>6, lane = tid&63;
  int wm = (wave>>1)*64, wn = (wave&1)*64;
  int lr = lane&15, q = lane>>4;
  int rs = tid>>2, cs = (tid&3)*8;
  f4_t acc[4][4] = {};
  for (int k0=0;k0<K;k0+=128){
    #pragma unroll
    for (int p=0;p<4;p++){
      #pragma unroll
      for (int s=0;s<2;s++){
        int row = s*64 + rs;
        async16(A + (size_t)(m0+row)*lda + k0 + p*32 + cs, As + p*4096 + s*2048 + tid*8);
        async16(W + (size_t)(n0+row)*ldw + k0 + p*32 + cs, Ws + p*4096 + s*2048 + tid*8);
      }
    }
    __syncthreads();
    #pragma unroll
    for (int p=0;p<4;p++){
      b8_t a[4], b[4];
      #pragma unroll
      for (int i=0;i<4;i++) a[i] = *(const b8_t*)(As + p*4096 + (wm+i*16+lr)*32 + q*8);
      #pragma unroll
      for (int j=0;j<4;j++) b[j] = *(const b8_t*)(Ws + p*4096 + (wn+j*16+lr)*32 + q*8);
      #pragma unroll
      for (int i=0;i<4;i++)
        #pragma unroll
        for (int j=0;j<4;j++)
          acc[i][j] = __builtin_amdgcn_mfma_f32_16x16x32_bf16(a[i], b[j], acc[i][j], 0,0,0);
    }
    __syncthreads();
  }
  #pragma unroll
  for (int i=0;i<4;i++)
  #pragma unroll
  for (int j=0;j<4;j++){
    int col = n0 + wn + j*16 + lr;
    int rb  = m0 + wm + i*16 + q*4;
    #pragma unroll
    for (int r=0;r<4;r++)
      Cbf[(size_t)(rb+r)*ldc + col] = (bf16_t)acc[i][j][r];
  }
}

// ---------- out_proj GEMM: h += y @ Wo^T ; 64x64 tile, BK=128 (4 panels) ----------
__global__ __launch_bounds__(256) void k_gout64(const bf16_t* __restrict__ A,
                                                const bf16_t* __restrict__ W,
                                                float* __restrict__ C){
  __shared__ bf16_t As[4*64*32];
  __shared__ bf16_t Ws[4*64*32];
  int tid = threadIdx.x;
  int m0 = blockIdx.y*64, n0 = blockIdx.x*64;
  int wave = tid>>6, lane = tid&63;
  int wm = (wave>>1)*32, wn = (wave&1)*32;
  int lr = lane&15, q = lane>>4;
  int e0 = tid*8, r0 = e0>>5, c0 = e0&31;
  f4_t acc[2][2] = {};
  for (int k0=0;k0<DI;k0+=128){
    #pragma unroll
    for (int p=0;p<4;p++){
      async16(A + (size_t)(m0+r0)*DI + k0 + p*32 + c0, As + p*2048 + e0);
      async16(W + (size_t)(n0+r0)*DI + k0 + p*32 + c0, Ws + p*2048 + e0);
    }
    __syncthreads();
    #pragma unroll
    for (int p=0;p<4;p++){
      b8_t a[2], b[2];
      #pragma unroll
      for (int i=0;i<2;i++) a[i] = *(const b8_t*)(As + p*2048 + (wm+i*16+lr)*32 + q*8);
      #pragma unroll
      for (int j=0;j<2;j++) b[j] = *(const b8_t*)(Ws + p*2048 + (wn+j*16+lr)*32 + q*8);
      #pragma unroll
      for (int i=0;i<2;i++)
        #pragma unroll
        for (int j=0;j<2;j++)
          acc[i][j] = __builtin_amdgcn_mfma_f32_16x16x32_bf16(a[i], b[j], acc[i][j], 0,0,0);
    }
    __syncthreads();
  }
  #pragma unroll
  for (int i=0;i<2;i++)
  #pragma unroll
  for (int j=0;j<2;j++){
    int col = n0 + wn + j*16 + lr;
    int rb  = m0 + wm + i*16 + q*4;
    #pragma unroll
    for (int r=0;r<4;r++){
      size_t off = (size_t)(rb+r)*DM + col;
      C[off] = C[off] + acc[i][j][r];
    }
  }
}

// ---------- x_proj GEMM, BK=128 (4 conv panels), split-K x4; emits xinbf ----------
__global__ __launch_bounds__(256) void k_dbc(const bf16_t* __restrict__ xzbf, const float* __restrict__ cw,
                                             const float* __restrict__ cb, const bf16_t* __restrict__ wxp,
                                             float* __restrict__ part, bf16_t* __restrict__ xinbf){
  __shared__ bf16_t As[4*64*32];
  __shared__ bf16_t Ws[4*64*32];
  int tid = threadIdx.x;
  int m0 = blockIdx.x*64;
  int z = blockIdx.y;
  int kbase = z*256;
  int wave = tid>>6, lane = tid&63;
  int wm = (wave>>1)*32, wn = (wave&1)*32;
  int lr = lane&15, q = lane>>4;
  int e0 = tid*8, r0 = e0>>5, c0 = e0&31;
  int gt = m0 + r0;              // global token
  int l  = gt & (L_-1);          // position within batch
  f4_t acc[2][2] = {};
  for (int k0=0;k0<256;k0+=128){
    #pragma unroll
    for (int p=0;p<4;p++){
      int ch = kbase + k0 + p*32 + c0;    // 8 channels
      float cv[8];
      #pragma unroll
      for (int c=0;c<8;c++) cv[c] = cb[ch+c];
      #pragma unroll
      for (int k=0;k<DC;k++){
        if (l + k - (DC-1) >= 0){
          b8_t xv = *(const b8_t*)(xzbf + (size_t)(gt + k - (DC-1))*(2*DI) + ch);
          #pragma unroll
          for (int c=0;c<8;c++) cv[c] += (float)xv[c] * cw[(ch+c)*DC + k];
        }
      }
      b8_t av;
      #pragma unroll
      for (int c=0;c<8;c++){ float s = cv[c]*sigmoidf_(cv[c]); av[c] = (bf16_t)s; }
      *(b8_t*)(As + p*2048 + e0) = av;
      *(b8_t*)(xinbf + (size_t)gt*DI + ch) = av;
      async16(wxp + (size_t)r0*DI + kbase + k0 + p*32 + c0, Ws + p*2048 + e0);
    }
    __syncthreads();
    #pragma unroll
    for (int p=0;p<4;p++){
      b8_t a[2], b[2];
      #pragma unroll
      for (int i=0;i<2;i++) a[i] = *(const b8_t*)(As + p*2048 + (wm+i*16+lr)*32 + q*8);
      #pragma unroll
      for (int j=0;j<2;j++) b[j] = *(const b8_t*)(Ws + p*2048 + (wn+j*16+lr)*32 + q*8);
      #pragma unroll
      for (int i=0;i<2;i++)
        #pragma unroll
        for (int j=0;j<2;j++)
          acc[i][j] = __builtin_amdgcn_mfma_f32_16x16x32_bf16(a[i], b[j], acc[i][j], 0,0,0);
    }
    __syncthreads();
  }
  float* P = part + (size_t)z*(B_*L_*64);
  #pragma unroll
  for (int i=0;i<2;i++)
  #pragma unroll
  for (int j=0;j<2;j++){
    int col = wn + j*16 + lr;
    int rb  = m0 + wm + i*16 + q*4;
    #pragma unroll
    for (int r=0;r<4;r++) P[(size_t)(rb+r)*64 + col] = acc[i][j][r];
  }
}

// ---------- fused: partial-reduce + dt-proj + softplus -> delta bf16; n-block0 writes dbc B/C f32 ----------
__global__ __launch_bounds__(256) void k_dt(const float* __restrict__ part, const bf16_t* __restrict__ wdt,
                                            const float* __restrict__ dtb, float* __restrict__ dbc,
                                            bf16_t* __restrict__ delta){
  __shared__ bf16_t As[64*32];
  __shared__ bf16_t Ws[64*32];
  int tid = threadIdx.x;
  int m0 = blockIdx.y*64, n0 = blockIdx.x*64;
  const size_t S = (size_t)B_*L_*64;
  int r0 = tid>>2, c0 = (tid&3)*8;
  int gt = m0 + r0;
  size_t base = (size_t)gt*64 + c0;
  f4_t s0 = *(const f4_t*)(part + base);
  f4_t s1 = *(const f4_t*)(part + base + 4);
  #pragma unroll
  for (int z=1;z<4;z++){
    s0 += *(const f4_t*)(part + z*S + base);
    s1 += *(const f4_t*)(part + z*S + base + 4);
  }
  b8_t av;
  #pragma unroll
  for (int c=0;c<4;c++){ av[c] = (bf16_t)s0[c]; av[4+c] = (bf16_t)s1[c]; }
  *(b8_t*)(As + tid*8) = av;
  if (n0 == 0){   // reduce + store B/C columns (32..64) in f32
    f4_t t0 = *(const f4_t*)(part + base + 32);
    f4_t t1 = *(const f4_t*)(part + base + 36);
    #pragma unroll
    for (int z=1;z<4;z++){
      t0 += *(const f4_t*)(part + z*S + base + 32);
      t1 += *(const f4_t*)(part + z*S + base + 36);
    }
    *(f4_t*)(dbc + base + 32) = t0;
    *(f4_t*)(dbc + base + 36) = t1;
  }
  async16(wdt + (size_t)(n0+r0)*DTR + c0, Ws + tid*8);
  __syncthreads();
  int wave = tid>>6, lane = tid&63;
  int wm = (wave>>1)*32, wn = (wave&1)*32;
  int lr = lane&15, q = lane>>4;
  b8_t a[2], b[2];
  #pragma unroll
  for (int i=0;i<2;i++) a[i] = *(const b8_t*)(As + (wm+i*16+lr)*32 + q*8);
  #pragma unroll
  for (int j=0;j<2;j++) b[j] = *(const b8_t*)(Ws + (wn+j*16+lr)*32 + q*8);
  f4_t acc[2][2] = {};
  #pragma unroll
  for (int i=0;i<2;i++)
    #pragma unroll
    for (int j=0;j<2;j++)
      acc[i][j] = __builtin_amdgcn_mfma_f32_16x16x32_bf16(a[i], b[j], acc[i][j], 0,0,0);
  #pragma unroll
  for (int i=0;i<2;i++)
  #pragma unroll
  for (int j=0;j<2;j++){
    int col = n0 + wn + j*16 + lr;
    int rb  = m0 + wm + i*16 + q*4;
    #pragma unroll
    for (int r=0;r<4;r++){
      float xv = acc[i][j][r] + dtb[col];
      float v = (xv>20.f)?xv:log1pf(__expf(xv));
      delta[(size_t)(rb+r)*DI + col] = (bf16_t)v;
    }
  }
}

// ---------- scan phase 1: LDS-staged chunk-local scan (h_in=0); bf16 state out ----------
__global__ __launch_bounds__(256) void k_scan_p1(const bf16_t* __restrict__ delta, const bf16_t* __restrict__ xin,
                                                 const float* __restrict__ dbc, const float* __restrict__ Alog,
                                                 bf16_t* __restrict__ hend, bf16_t* __restrict__ aprod){
  __shared__ bf16_t des[CHUNK][256];
  __shared__ bf16_t xs[CHUNK][256];
  __shared__ float Bs[CHUNK][DS];
  int tid = threadIdx.x;
  int blk = blockIdx.x;
  int chgrp = blk & 3;
  int chunk = (blk>>2) & (NCHK-1);
  int b = blk >> 7;
  int ch0 = chgrp<<8;
  int ch = ch0 + tid;
  int t0 = (b<<9) + chunk*CHUNK;
  #pragma unroll
  for (int idx=tid; idx<CHUNK*32; idx+=256){
    int row = idx>>5, c = (idx&31)*8;
    *(b8_t*)(&des[row][c]) = *(const b8_t*)(delta + (size_t)(t0+row)*DI + ch0 + c);
    *(b8_t*)(&xs[row][c])  = *(const b8_t*)(xin   + (size_t)(t0+row)*DI + ch0 + c);
  }
  {
    int ll = tid>>4, n = tid&15;
    Bs[ll][n] = dbc[(t0+ll)*64 + DTR + n];
  }
  __syncthreads();
  float An2[DS], h[DS];
  const f4_t* Ap = (const f4_t*)(Alog + ch*DS);
  #pragma unroll
  for (int v=0;v<4;v++){
    f4_t a4 = Ap[v];
    #pragma unroll
    for (int k=0;k<4;k++){ An2[v*4+k] = -__expf(a4[k])*LOG2E; h[v*4+k]=0.f; }
  }
  float sde = 0.f;
  #pragma unroll
  for (int l=0;l<CHUNK;l++){
    float de = (float)des[l][tid];
    float xv = (float)xs[l][tid];
    float dx = de*xv;
    sde += de;
    #pragma unroll
    for (int n=0;n<DS;n++){
      float dA = exp2f(de*An2[n]);
      h[n] = dA*h[n] + dx*Bs[l][n];
    }
  }
  size_t base = ((size_t)chunk*(B_*DI) + (b<<10) + ch)*DS;
  b8_t hv[2], av[2];
  #pragma unroll
  for (int v=0;v<2;v++)
    #pragma unroll
    for (int k=0;k<8;k++){
      hv[v][k] = (bf16_t)h[v*8+k];
      av[v][k] = (bf16_t)exp2f(An2[v*8+k]*sde);
    }
  ((b8_t*)(hend + base))[0] = hv[0]; ((b8_t*)(hend + base))[1] = hv[1];
  ((b8_t*)(aprod + base))[0] = av[0]; ((b8_t*)(aprod + base))[1] = av[1];
}

// ---------- scan phase 2: combine chunk transitions (bf16 in, bf16 hin out into aprod) ----------
__global__ __launch_bounds__(256) void k_scan_p2(const bf16_t* __restrict__ hend, bf16_t* __restrict__ ap_hin){
  int g = blockIdx.x*256 + threadIdx.x;   // B_*DI*DS
  float h = 0.f;
  for (int c=0;c<NCHK;c++){
    size_t off = (size_t)c*(B_*DI*DS) + g;
    float a = (float)ap_hin[off];
    float e = (float)hend[off];
    ap_hin[off] = (bf16_t)h;
    h = a*h + e;
  }
}

// ---------- scan phase 3: LDS-staged rerun with h_in, produce gated y (bf16) ----------
__global__ __launch_bounds__(256) void k_scan_p3(const bf16_t* __restrict__ delta, const bf16_t* __restrict__ xz,
                                                 const bf16_t* __restrict__ xin,
                                                 const float* __restrict__ dbc, const float* __restrict__ Alog,
                                                 const bf16_t* __restrict__ hin, const float* __restrict__ Dp,
                                                 bf16_t* __restrict__ ybf){
  __shared__ bf16_t des[CHUNK][256];
  __shared__ bf16_t xs[CHUNK][256];
  __shared__ bf16_t zs[CHUNK][256];
  __shared__ float Bs[CHUNK][DS];
  __shared__ float Cs[CHUNK][DS];
  int tid = threadIdx.x;
  int blk = blockIdx.x;
  int chgrp = blk & 3;
  int chunk = (blk>>2) & (NCHK-1);
  int b = blk >> 7;
  int ch0 = chgrp<<8;
  int ch = ch0 + tid;
  int t0 = (b<<9) + chunk*CHUNK;
  #pragma unroll
  for (int idx=tid; idx<CHUNK*32; idx+=256){
    int row = idx>>5, c = (idx&31)*8;
    *(b8_t*)(&des[row][c]) = *(const b8_t*)(delta + (size_t)(t0+row)*DI + ch0 + c);
    *(b8_t*)(&xs[row][c])  = *(const b8_t*)(xin   + (size_t)(t0+row)*DI + ch0 + c);
    *(b8_t*)(&zs[row][c])  = *(const b8_t*)(xz + (size_t)(t0+row)*(2*DI) + DI + ch0 + c);
  }
  {
    int ll = tid>>4, n = tid&15;
    Bs[ll][n] = dbc[(t0+ll)*64 + DTR + n];
    Cs[ll][n] = dbc[(t0+ll)*64 + DTR + DS + n];
  }
  __syncthreads();
  float An2[DS], h[DS];
  const f4_t* Ap = (const f4_t*)(Alog + ch*DS);
  size_t base = ((size_t)chunk*(B_*DI) + (b<<10) + ch)*DS;
  b8_t h0 = ((const b8_t*)(hin + base))[0];
  b8_t h1 = ((const b8_t*)(hin + base))[1];
  #pragma unroll
  for (int v=0;v<4;v++){
    f4_t a4 = Ap[v];
    #pragma unroll
    for (int k=0;k<4;k++){
      An2[v*4+k] = -__expf(a4[k])*LOG2E;
      int idx = v*4+k;
      h[idx] = (idx<8) ? (float)h0[idx] : (float)h1[idx-8];
    }
  }
  float Dv = Dp[ch];
  bf16_t* yp = ybf + (size_t)t0*DI + ch;
  #pragma unroll
  for (int l=0;l<CHUNK;l++){
    float de = (float)des[l][tid];
    float zv = (float)zs[l][tid];
    float xv = (float)xs[l][tid];
    float dx = de*xv;
    float y = 0.f;
    #pragma unroll
    for (int n=0;n<DS;n++){
      float dA = exp2f(de*An2[n]);
      h[n] = dA*h[n] + dx*Bs[l][n];
      y += h[n]*Cs[l][n];
    }
    y = (y + Dv*xv) * (zv * sigmoidf_(zv));
    yp[(size_t)l*DI] = (bf16_t)y;
  }
}

// ---------- head ----------
__global__ __launch_bounds__(256) void k_head(const float* __restrict__ h, const float* __restrict__ hw,
                                              const float* __restrict__ hb, float* __restrict__ out){
  int wave = threadIdx.x>>6, lane = threadIdx.x&63;
  int gw = blockIdx.x*4 + wave;                    // < B_*HOR
  int b = gw / HOR, hh = gw % HOR;
  const float* hp = h + ((size_t)b*L_ + (L_-1))*DM;
  const float* wp = hw + (size_t)hh*DM;
  float s = 0.f;
  #pragma unroll
  for (int k=0;k<DM;k+=64) s += hp[k+lane]*wp[k+lane];
  #pragma unroll
  for (int m=32;m;m>>=1) s += __shfl_xor(s, m);
  if (lane==0) out[gw] = s + hb[hh];
}

extern "C" void kernel_launch(void* const* d_in, const int* in_sizes, int n_in,
                              void* d_out, int out_size, void* d_ws, size_t ws_size,
                              hipStream_t stream){
  const float* x    = (const float*)d_in[0];
  const float* ew   = (const float*)d_in[1];
  const float* eb   = (const float*)d_in[2];
  const float* nw   = (const float*)d_in[3];
  const float* ipw  = (const float*)d_in[4];
  const float* cw   = (const float*)d_in[5];
  const float* cb   = (const float*)d_in[6];
  const float* xpw  = (const float*)d_in[7];
  const float* dtw  = (const float*)d_in[8];
  const float* dtb  = (const float*)d_in[9];
  const float* alog = (const float*)d_in[10];
  const float* Dp   = (const float*)d_in[11];
  const float* opw  = (const float*)d_in[12];
  const float* hw   = (const float*)d_in[13];
  const float* hb   = (const float*)d_in[14];
  float* out = (float*)d_out;

  char* ws = (char*)d_ws;
  size_t o = 0;
  float*  h      = (float*)(ws + o);  o += (size_t)8<<20;    // B*L*DM f32
  bf16_t* hnorm  = (bf16_t*)(ws + o); o += (size_t)4<<20;
  bf16_t* xzbf   = (bf16_t*)(ws + o); o += (size_t)16<<20;   // B*L*2DI bf16
  bf16_t* xinbf  = (bf16_t*)(ws + o); o += (size_t)8<<20;
  bf16_t* delta  = (bf16_t*)(ws + o); o += (size_t)8<<20;    // B*L*DI bf16
  bf16_t* ybf    = (bf16_t*)(ws + o); o += (size_t)8<<20;
  float*  dbc    = (float*)(ws + o);  o += (size_t)1<<20;    // only cols 32..63 used
  float*  dbcp   = (float*)(ws + o);  o += (size_t)4<<20;    // 4 split-K partials
  bf16_t* w_in   = (bf16_t*)(ws + o); o += (size_t)8<<20;
  bf16_t* w_out  = (bf16_t*)(ws + o); o += (size_t)4<<20;
  bf16_t* w_xp   = (bf16_t*)(ws + o); o += (size_t)1<<19;
  bf16_t* w_dt   = (bf16_t*)(ws + o); o += (size_t)1<<18;
  bf16_t* hend   = (bf16_t*)(ws + o); o += (size_t)8<<20;    // NCHK*B*DI*DS bf16
  bf16_t* aphin  = (bf16_t*)(ws + o); o += (size_t)8<<20;    // ~86 MB total

  k_cvtall<<<6528,256,0,stream>>>(ipw, w_in, xpw, w_xp, dtw, w_dt, opw, w_out);
  k_embed<<<(B_*L_*DM)/256,256,0,stream>>>(x, ew, eb, h);

  for (int i=0;i<NL;i++){
    k_rms<<<B_*L_,256,0,stream>>>(h, nw + i*DM, hnorm);
    // xz(bf16) = hnorm @ in_proj^T   (M=4096,N=2048,K=512) -- 512 blocks of 128x128, BK=128
    k_g128<<<dim3(2*DI/128, B_*L_/128),256,0,stream>>>(
        hnorm, DM, w_in + (size_t)i*2*DI*DM, DM, DM, xzbf, 2*DI);
    // dbc partials = silu(conv(xz)) @ x_proj^T  (split-K x4, BK=128, conv fused, xinbf emitted)
    k_dbc<<<dim3(B_*L_/64, 4),256,0,stream>>>(xzbf, cw + i*DI*DC, cb + i*DI,
                                              w_xp + (size_t)i*64*DI, dbcp, xinbf);
    // delta(bf16) = softplus(sum(partials)[:, :32] @ dt_w^T + dt_b); dbc B/C by n-block 0
    k_dt<<<dim3(DI/64, B_*L_/64),256,0,stream>>>(dbcp, w_dt + (size_t)i*DI*DTR,
                                                 dtb + i*DI, dbc, delta);
    // chunked selective scan (3-phase, LDS-staged, CHUNK=16)
    k_scan_p1<<<B_*NCHK*4,256,0,stream>>>(delta, xinbf, dbc, alog + i*DI*DS, hend, aphin);
    k_scan_p2<<<(B_*DI*DS)/256,256,0,stream>>>(hend, aphin);
    k_scan_p3<<<B_*NCHK*4,256,0,stream>>>(delta, xzbf, xinbf, dbc, alog + i*DI*DS,
                                          aphin, Dp + i*DI, ybf);
    // h += y @ out_proj^T (M=4096,N=512,K=1024) -- 512 blocks, BK=128
    k_gout64<<<dim3(DM/64, B_*L_/64),256,0,stream>>>(ybf, w_out + (size_t)i*DM*DI, h);
  }
  k_head<<<(B_*HOR)/4,256,0,stream>>>(h, hw, hb, out);
}

// Round 15
// 606.193 us; speedup vs baseline: 1.0688x; 1.0003x over previous
//
#include <hip/hip_runtime.h>
#include <hip/hip_bf16.h>

#define B_  8
#define L_  512
#define DM  512
#define NL  4
#define DS  16
#define HOR 96
#define DC  4
#define DI  1024
#define DTR 32

#define CHUNK 16
#define NCHK (L_/CHUNK)   // 32

typedef __bf16 bf16_t;
typedef __bf16 b8_t __attribute__((ext_vector_type(8)));
typedef float  f4_t __attribute__((ext_vector_type(4)));

#define LOG2E 1.44269504088896f

__device__ __forceinline__ float sigmoidf_(float x){ return 1.f/(1.f+__expf(-x)); }

__device__ __forceinline__ void async16(const bf16_t* g, bf16_t* l){
  __builtin_amdgcn_global_load_lds((const __attribute__((address_space(1))) void*)g,
                                   (__attribute__((address_space(3))) void*)l, 16, 0, 0);
}

// ---------- fused prologue: weight f32->bf16 convert + embed ----------
__global__ __launch_bounds__(256) void k_prep(const float* __restrict__ p0, bf16_t* __restrict__ o0,
                                              const float* __restrict__ p1, bf16_t* __restrict__ o1,
                                              const float* __restrict__ p2, bf16_t* __restrict__ o2,
                                              const float* __restrict__ p3, bf16_t* __restrict__ o3,
                                              const float* __restrict__ x, const float* __restrict__ ew,
                                              const float* __restrict__ eb, float* __restrict__ h){
  int blk = blockIdx.x;
  if (blk < 6528){               // weight convert: 1671168 v4 items
    int j = blk*256 + threadIdx.x;
    const int S0=1048576, S1=65536, S2=32768;
    const float* src; bf16_t* dst;
    if (j < S0){ src=p0; dst=o0; }
    else if ((j-=S0) < S1){ src=p1; dst=o1; }
    else if ((j-=S1) < S2){ src=p2; dst=o2; }
    else { j-=S2; src=p3; dst=o3; }
    f4_t v = ((const f4_t*)src)[j];
    bf16_t* o = dst + (size_t)j*4;
    o[0]=(bf16_t)v[0]; o[1]=(bf16_t)v[1]; o[2]=(bf16_t)v[2]; o[3]=(bf16_t)v[3];
  } else {                       // embed: 524288 v4 items (B*L*DM / 4)
    int j = (blk-6528)*256 + threadIdx.x;
    int idx = j*4;
    int d = idx & (DM-1); int t = idx >> 9;
    float xv = x[t];
    f4_t w = *(const f4_t*)(ew + d);
    f4_t b = *(const f4_t*)(eb + d);
    f4_t v;
    #pragma unroll
    for (int c=0;c<4;c++) v[c] = xv*w[c] + b[c];
    *(f4_t*)(h + idx) = v;
  }
}

// ---------- rmsnorm (fp32 in, bf16 out) ----------
__global__ __launch_bounds__(256) void k_rms(const float* __restrict__ h, const float* __restrict__ w,
                                             bf16_t* __restrict__ o){
  int t = blockIdx.x; int tid = threadIdx.x;
  const float* hp = h + (size_t)t*DM;
  float v0 = hp[tid], v1 = hp[tid+256];
  float s = v0*v0 + v1*v1;
  #pragma unroll
  for (int m=32;m;m>>=1) s += __shfl_xor(s, m);
  __shared__ float red[4];
  if ((tid&63)==0) red[tid>>6]=s;
  __syncthreads();
  float tot = red[0]+red[1]+red[2]+red[3];
  float sc = rsqrtf(tot*(1.f/DM) + 1e-5f);
  o[(size_t)t*DM + tid]       = (bf16_t)(v0*sc*w[tid]);
  o[(size_t)t*DM + tid + 256] = (bf16_t)(v1*sc*w[tid+256]);
}

// ---------- 128x128 GEMM (in_proj), BK=128: 64 MFMA per barrier pair, 4 outer iters ----------
__global__ __launch_bounds__(256) void k_g128(const bf16_t* __restrict__ A, int lda,
                                              const bf16_t* __restrict__ W, int ldw,
                                              int K, bf16_t* __restrict__ Cbf, int ldc){
  __shared__ bf16_t As[4*128*32];
  __shared__ bf16_t Ws[4*128*32];
  int tid = threadIdx.x;
  int m0 = blockIdx.y*128, n0 = blockIdx.x*128;
  int wave = tid>>6, lane = tid&63;
  int wm = (wave>>1)*64, wn = (wave&1)*64;
  int lr = lane&15, q = lane>>4;
  int rs = tid>>2, cs = (tid&3)*8;
  f4_t acc[4][4] = {};
  for (int k0=0;k0<K;k0+=128){
    #pragma unroll
    for (int p=0;p<4;p++){
      #pragma unroll
      for (int s=0;s<2;s++){
        int row = s*64 + rs;
        async16(A + (size_t)(m0+row)*lda + k0 + p*32 + cs, As + p*4096 + s*2048 + tid*8);
        async16(W + (size_t)(n0+row)*ldw + k0 + p*32 + cs, Ws + p*4096 + s*2048 + tid*8);
      }
    }
    __syncthreads();
    #pragma unroll
    for (int p=0;p<4;p++){
      b8_t a[4], b[4];
      #pragma unroll
      for (int i=0;i<4;i++) a[i] = *(const b8_t*)(As + p*4096 + (wm+i*16+lr)*32 + q*8);
      #pragma unroll
      for (int j=0;j<4;j++) b[j] = *(const b8_t*)(Ws + p*4096 + (wn+j*16+lr)*32 + q*8);
      #pragma unroll
      for (int i=0;i<4;i++)
        #pragma unroll
        for (int j=0;j<4;j++)
          acc[i][j] = __builtin_amdgcn_mfma_f32_16x16x32_bf16(a[i], b[j], acc[i][j], 0,0,0);
    }
    __syncthreads();
  }
  #pragma unroll
  for (int i=0;i<4;i++)
  #pragma unroll
  for (int j=0;j<4;j++){
    int col = n0 + wn + j*16 + lr;
    int rb  = m0 + wm + i*16 + q*4;
    #pragma unroll
    for (int r=0;r<4;r++)
      Cbf[(size_t)(rb+r)*ldc + col] = (bf16_t)acc[i][j][r];
  }
}

// ---------- out_proj GEMM: h += y @ Wo^T ; 64x64 tile, BK=256 (8 panels), 4 outer iters ----------
__global__ __launch_bounds__(256) void k_gout64(const bf16_t* __restrict__ A,
                                                const bf16_t* __restrict__ W,
                                                float* __restrict__ C){
  __shared__ bf16_t As[8*64*32];
  __shared__ bf16_t Ws[8*64*32];
  int tid = threadIdx.x;
  int m0 = blockIdx.y*64, n0 = blockIdx.x*64;
  int wave = tid>>6, lane = tid&63;
  int wm = (wave>>1)*32, wn = (wave&1)*32;
  int lr = lane&15, q = lane>>4;
  int e0 = tid*8, r0 = e0>>5, c0 = e0&31;
  f4_t acc[2][2] = {};
  for (int k0=0;k0<DI;k0+=256){
    #pragma unroll
    for (int p=0;p<8;p++){
      async16(A + (size_t)(m0+r0)*DI + k0 + p*32 + c0, As + p*2048 + e0);
      async16(W + (size_t)(n0+r0)*DI + k0 + p*32 + c0, Ws + p*2048 + e0);
    }
    __syncthreads();
    #pragma unroll
    for (int p=0;p<8;p++){
      b8_t a[2], b[2];
      #pragma unroll
      for (int i=0;i<2;i++) a[i] = *(const b8_t*)(As + p*2048 + (wm+i*16+lr)*32 + q*8);
      #pragma unroll
      for (int j=0;j<2;j++) b[j] = *(const b8_t*)(Ws + p*2048 + (wn+j*16+lr)*32 + q*8);
      #pragma unroll
      for (int i=0;i<2;i++)
        #pragma unroll
        for (int j=0;j<2;j++)
          acc[i][j] = __builtin_amdgcn_mfma_f32_16x16x32_bf16(a[i], b[j], acc[i][j], 0,0,0);
    }
    __syncthreads();
  }
  #pragma unroll
  for (int i=0;i<2;i++)
  #pragma unroll
  for (int j=0;j<2;j++){
    int col = n0 + wn + j*16 + lr;
    int rb  = m0 + wm + i*16 + q*4;
    #pragma unroll
    for (int r=0;r<4;r++){
      size_t off = (size_t)(rb+r)*DM + col;
      C[off] = C[off] + acc[i][j][r];
    }
  }
}

// ---------- x_proj GEMM, split-K x8 (K-slice=128, single pass, 4 conv panels); emits xinbf ----------
__global__ __launch_bounds__(256) void k_dbc(const bf16_t* __restrict__ xzbf, const float* __restrict__ cw,
                                             const float* __restrict__ cb, const bf16_t* __restrict__ wxp,
                                             float* __restrict__ part, bf16_t* __restrict__ xinbf){
  __shared__ bf16_t As[4*64*32];
  __shared__ bf16_t Ws[4*64*32];
  int tid = threadIdx.x;
  int m0 = blockIdx.x*64;
  int z = blockIdx.y;
  int kbase = z*128;
  int wave = tid>>6, lane = tid&63;
  int wm = (wave>>1)*32, wn = (wave&1)*32;
  int lr = lane&15, q = lane>>4;
  int e0 = tid*8, r0 = e0>>5, c0 = e0&31;
  int gt = m0 + r0;              // global token
  int l  = gt & (L_-1);          // position within batch
  f4_t acc[2][2] = {};
  #pragma unroll
  for (int p=0;p<4;p++){
    int ch = kbase + p*32 + c0;  // 8 channels
    float cv[8];
    #pragma unroll
    for (int c=0;c<8;c++) cv[c] = cb[ch+c];
    #pragma unroll
    for (int k=0;k<DC;k++){
      if (l + k - (DC-1) >= 0){
        b8_t xv = *(const b8_t*)(xzbf + (size_t)(gt + k - (DC-1))*(2*DI) + ch);
        #pragma unroll
        for (int c=0;c<8;c++) cv[c] += (float)xv[c] * cw[(ch+c)*DC + k];
      }
    }
    b8_t av;
    #pragma unroll
    for (int c=0;c<8;c++){ float s = cv[c]*sigmoidf_(cv[c]); av[c] = (bf16_t)s; }
    *(b8_t*)(As + p*2048 + e0) = av;
    *(b8_t*)(xinbf + (size_t)gt*DI + ch) = av;
    async16(wxp + (size_t)r0*DI + kbase + p*32 + c0, Ws + p*2048 + e0);
  }
  __syncthreads();
  #pragma unroll
  for (int p=0;p<4;p++){
    b8_t a[2], b[2];
    #pragma unroll
    for (int i=0;i<2;i++) a[i] = *(const b8_t*)(As + p*2048 + (wm+i*16+lr)*32 + q*8);
    #pragma unroll
    for (int j=0;j<2;j++) b[j] = *(const b8_t*)(Ws + p*2048 + (wn+j*16+lr)*32 + q*8);
    #pragma unroll
    for (int i=0;i<2;i++)
      #pragma unroll
      for (int j=0;j<2;j++)
        acc[i][j] = __builtin_amdgcn_mfma_f32_16x16x32_bf16(a[i], b[j], acc[i][j], 0,0,0);
  }
  float* P = part + (size_t)z*(B_*L_*64);
  #pragma unroll
  for (int i=0;i<2;i++)
  #pragma unroll
  for (int j=0;j<2;j++){
    int col = wn + j*16 + lr;
    int rb  = m0 + wm + i*16 + q*4;
    #pragma unroll
    for (int r=0;r<4;r++) P[(size_t)(rb+r)*64 + col] = acc[i][j][r];
  }
}

// ---------- fused: partial-reduce(x8) + dt-proj + softplus -> delta bf16; n-block0 writes dbc B/C f32 ----------
__global__ __launch_bounds__(256) void k_dt(const float* __restrict__ part, const bf16_t* __restrict__ wdt,
                                            const float* __restrict__ dtb, float* __restrict__ dbc,
                                            bf16_t* __restrict__ delta){
  __shared__ bf16_t As[64*32];
  __shared__ bf16_t Ws[64*32];
  int tid = threadIdx.x;
  int m0 = blockIdx.y*64, n0 = blockIdx.x*64;
  const size_t S = (size_t)B_*L_*64;
  int r0 = tid>>2, c0 = (tid&3)*8;
  int gt = m0 + r0;
  size_t base = (size_t)gt*64 + c0;
  f4_t s0 = *(const f4_t*)(part + base);
  f4_t s1 = *(const f4_t*)(part + base + 4);
  #pragma unroll
  for (int z=1;z<8;z++){
    s0 += *(const f4_t*)(part + z*S + base);
    s1 += *(const f4_t*)(part + z*S + base + 4);
  }
  b8_t av;
  #pragma unroll
  for (int c=0;c<4;c++){ av[c] = (bf16_t)s0[c]; av[4+c] = (bf16_t)s1[c]; }
  *(b8_t*)(As + tid*8) = av;
  if (n0 == 0){   // reduce + store B/C columns (32..64) in f32
    f4_t t0 = *(const f4_t*)(part + base + 32);
    f4_t t1 = *(const f4_t*)(part + base + 36);
    #pragma unroll
    for (int z=1;z<8;z++){
      t0 += *(const f4_t*)(part + z*S + base + 32);
      t1 += *(const f4_t*)(part + z*S + base + 36);
    }
    *(f4_t*)(dbc + base + 32) = t0;
    *(f4_t*)(dbc + base + 36) = t1;
  }
  async16(wdt + (size_t)(n0+r0)*DTR + c0, Ws + tid*8);
  __syncthreads();
  int wave = tid>>6, lane = tid&63;
  int wm = (wave>>1)*32, wn = (wave&1)*32;
  int lr = lane&15, q = lane>>4;
  b8_t a[2], b[2];
  #pragma unroll
  for (int i=0;i<2;i++) a[i] = *(const b8_t*)(As + (wm+i*16+lr)*32 + q*8);
  #pragma unroll
  for (int j=0;j<2;j++) b[j] = *(const b8_t*)(Ws + (wn+j*16+lr)*32 + q*8);
  f4_t acc[2][2] = {};
  #pragma unroll
  for (int i=0;i<2;i++)
    #pragma unroll
    for (int j=0;j<2;j++)
      acc[i][j] = __builtin_amdgcn_mfma_f32_16x16x32_bf16(a[i], b[j], acc[i][j], 0,0,0);
  #pragma unroll
  for (int i=0;i<2;i++)
  #pragma unroll
  for (int j=0;j<2;j++){
    int col = n0 + wn + j*16 + lr;
    int rb  = m0 + wm + i*16 + q*4;
    #pragma unroll
    for (int r=0;r<4;r++){
      float xv = acc[i][j][r] + dtb[col];
      float v = (xv>20.f)?xv:log1pf(__expf(xv));
      delta[(size_t)(rb+r)*DI + col] = (bf16_t)v;
    }
  }
}

// ---------- scan phase 1: LDS-staged chunk-local scan (h_in=0); bf16 state out ----------
__global__ __launch_bounds__(256) void k_scan_p1(const bf16_t* __restrict__ delta, const bf16_t* __restrict__ xin,
                                                 const float* __restrict__ dbc, const float* __restrict__ Alog,
                                                 bf16_t* __restrict__ hend, bf16_t* __restrict__ aprod){
  __shared__ bf16_t des[CHUNK][256];
  __shared__ bf16_t xs[CHUNK][256];
  __shared__ float Bs[CHUNK][DS];
  int tid = threadIdx.x;
  int blk = blockIdx.x;
  int chgrp = blk & 3;
  int chunk = (blk>>2) & (NCHK-1);
  int b = blk >> 7;
  int ch0 = chgrp<<8;
  int ch = ch0 + tid;
  int t0 = (b<<9) + chunk*CHUNK;
  #pragma unroll
  for (int idx=tid; idx<CHUNK*32; idx+=256){
    int row = idx>>5, c = (idx&31)*8;
    *(b8_t*)(&des[row][c]) = *(const b8_t*)(delta + (size_t)(t0+row)*DI + ch0 + c);
    *(b8_t*)(&xs[row][c])  = *(const b8_t*)(xin   + (size_t)(t0+row)*DI + ch0 + c);
  }
  {
    int ll = tid>>4, n = tid&15;
    Bs[ll][n] = dbc[(t0+ll)*64 + DTR + n];
  }
  __syncthreads();
  float An2[DS], h[DS];
  const f4_t* Ap = (const f4_t*)(Alog + ch*DS);
  #pragma unroll
  for (int v=0;v<4;v++){
    f4_t a4 = Ap[v];
    #pragma unroll
    for (int k=0;k<4;k++){ An2[v*4+k] = -__expf(a4[k])*LOG2E; h[v*4+k]=0.f; }
  }
  float sde = 0.f;
  #pragma unroll
  for (int l=0;l<CHUNK;l++){
    float de = (float)des[l][tid];
    float xv = (float)xs[l][tid];
    float dx = de*xv;
    sde += de;
    #pragma unroll
    for (int n=0;n<DS;n++){
      float dA = exp2f(de*An2[n]);
      h[n] = dA*h[n] + dx*Bs[l][n];
    }
  }
  size_t base = ((size_t)chunk*(B_*DI) + (b<<10) + ch)*DS;
  b8_t hv[2], av[2];
  #pragma unroll
  for (int v=0;v<2;v++)
    #pragma unroll
    for (int k=0;k<8;k++){
      hv[v][k] = (bf16_t)h[v*8+k];
      av[v][k] = (bf16_t)exp2f(An2[v*8+k]*sde);
    }
  ((b8_t*)(hend + base))[0] = hv[0]; ((b8_t*)(hend + base))[1] = hv[1];
  ((b8_t*)(aprod + base))[0] = av[0]; ((b8_t*)(aprod + base))[1] = av[1];
}

// ---------- scan phase 2: combine chunk transitions (bf16 in, bf16 hin out into aprod) ----------
__global__ __launch_bounds__(256) void k_scan_p2(const bf16_t* __restrict__ hend, bf16_t* __restrict__ ap_hin){
  int g = blockIdx.x*256 + threadIdx.x;   // B_*DI*DS
  float h = 0.f;
  for (int c=0;c<NCHK;c++){
    size_t off = (size_t)c*(B_*DI*DS) + g;
    float a = (float)ap_hin[off];
    float e = (float)hend[off];
    ap_hin[off] = (bf16_t)h;
    h = a*h + e;
  }
}

// ---------- scan phase 3: LDS-staged rerun with h_in, produce gated y (bf16) ----------
__global__ __launch_bounds__(256) void k_scan_p3(const bf16_t* __restrict__ delta, const bf16_t* __restrict__ xz,
                                                 const bf16_t* __restrict__ xin,
                                                 const float* __restrict__ dbc, const float* __restrict__ Alog,
                                                 const bf16_t* __restrict__ hin, const float* __restrict__ Dp,
                                                 bf16_t* __restrict__ ybf){
  __shared__ bf16_t des[CHUNK][256];
  __shared__ bf16_t xs[CHUNK][256];
  __shared__ bf16_t zs[CHUNK][256];
  __shared__ float Bs[CHUNK][DS];
  __shared__ float Cs[CHUNK][DS];
  int tid = threadIdx.x;
  int blk = blockIdx.x;
  int chgrp = blk & 3;
  int chunk = (blk>>2) & (NCHK-1);
  int b = blk >> 7;
  int ch0 = chgrp<<8;
  int ch = ch0 + tid;
  int t0 = (b<<9) + chunk*CHUNK;
  #pragma unroll
  for (int idx=tid; idx<CHUNK*32; idx+=256){
    int row = idx>>5, c = (idx&31)*8;
    *(b8_t*)(&des[row][c]) = *(const b8_t*)(delta + (size_t)(t0+row)*DI + ch0 + c);
    *(b8_t*)(&xs[row][c])  = *(const b8_t*)(xin   + (size_t)(t0+row)*DI + ch0 + c);
    *(b8_t*)(&zs[row][c])  = *(const b8_t*)(xz + (size_t)(t0+row)*(2*DI) + DI + ch0 + c);
  }
  {
    int ll = tid>>4, n = tid&15;
    Bs[ll][n] = dbc[(t0+ll)*64 + DTR + n];
    Cs[ll][n] = dbc[(t0+ll)*64 + DTR + DS + n];
  }
  __syncthreads();
  float An2[DS], h[DS];
  const f4_t* Ap = (const f4_t*)(Alog + ch*DS);
  size_t base = ((size_t)chunk*(B_*DI) + (b<<10) + ch)*DS;
  b8_t h0 = ((const b8_t*)(hin + base))[0];
  b8_t h1 = ((const b8_t*)(hin + base))[1];
  #pragma unroll
  for (int v=0;v<4;v++){
    f4_t a4 = Ap[v];
    #pragma unroll
    for (int k=0;k<4;k++){
      An2[v*4+k] = -__expf(a4[k])*LOG2E;
      int idx = v*4+k;
      h[idx] = (idx<8) ? (float)h0[idx] : (float)h1[idx-8];
    }
  }
  float Dv = Dp[ch];
  bf16_t* yp = ybf + (size_t)t0*DI + ch;
  #pragma unroll
  for (int l=0;l<CHUNK;l++){
    float de = (float)des[l][tid];
    float zv = (float)zs[l][tid];
    float xv = (float)xs[l][tid];
    float dx = de*xv;
    float y = 0.f;
    #pragma unroll
    for (int n=0;n<DS;n++){
      float dA = exp2f(de*An2[n]);
      h[n] = dA*h[n] + dx*Bs[l][n];
      y += h[n]*Cs[l][n];
    }
    y = (y + Dv*xv) * (zv * sigmoidf_(zv));
    yp[(size_t)l*DI] = (bf16_t)y;
  }
}

// ---------- head ----------
__global__ __launch_bounds__(256) void k_head(const float* __restrict__ h, const float* __restrict__ hw,
                                              const float* __restrict__ hb, float* __restrict__ out){
  int wave = threadIdx.x>>6, lane = threadIdx.x&63;
  int gw = blockIdx.x*4 + wave;                    // < B_*HOR
  int b = gw / HOR, hh = gw % HOR;
  const float* hp = h + ((size_t)b*L_ + (L_-1))*DM;
  const float* wp = hw + (size_t)hh*DM;
  float s = 0.f;
  #pragma unroll
  for (int k=0;k<DM;k+=64) s += hp[k+lane]*wp[k+lane];
  #pragma unroll
  for (int m=32;m;m>>=1) s += __shfl_xor(s, m);
  if (lane==0) out[gw] = s + hb[hh];
}

extern "C" void kernel_launch(void* const* d_in, const int* in_sizes, int n_in,
                              void* d_out, int out_size, void* d_ws, size_t ws_size,
                              hipStream_t stream){
  const float* x    = (const float*)d_in[0];
  const float* ew   = (const float*)d_in[1];
  const float* eb   = (const float*)d_in[2];
  const float* nw   = (const float*)d_in[3];
  const float* ipw  = (const float*)d_in[4];
  const float* cw   = (const float*)d_in[5];
  const float* cb   = (const float*)d_in[6];
  const float* xpw  = (const float*)d_in[7];
  const float* dtw  = (const float*)d_in[8];
  const float* dtb  = (const float*)d_in[9];
  const float* alog = (const float*)d_in[10];
  const float* Dp   = (const float*)d_in[11];
  const float* opw  = (const float*)d_in[12];
  const float* hw   = (const float*)d_in[13];
  const float* hb   = (const float*)d_in[14];
  float* out = (float*)d_out;

  char* ws = (char*)d_ws;
  size_t o = 0;
  float*  h      = (float*)(ws + o);  o += (size_t)8<<20;    // B*L*DM f32
  bf16_t* hnorm  = (bf16_t*)(ws + o); o += (size_t)4<<20;
  bf16_t* xzbf   = (bf16_t*)(ws + o); o += (size_t)16<<20;   // B*L*2DI bf16
  bf16_t* xinbf  = (bf16_t*)(ws + o); o += (size_t)8<<20;
  bf16_t* delta  = (bf16_t*)(ws + o); o += (size_t)8<<20;    // B*L*DI bf16
  bf16_t* ybf    = (bf16_t*)(ws + o); o += (size_t)8<<20;
  float*  dbc    = (float*)(ws + o);  o += (size_t)1<<20;    // only cols 32..63 used
  float*  dbcp   = (float*)(ws + o);  o += (size_t)8<<20;    // 8 split-K partials
  bf16_t* w_in   = (bf16_t*)(ws + o); o += (size_t)8<<20;
  bf16_t* w_out  = (bf16_t*)(ws + o); o += (size_t)4<<20;
  bf16_t* w_xp   = (bf16_t*)(ws + o); o += (size_t)1<<19;
  bf16_t* w_dt   = (bf16_t*)(ws + o); o += (size_t)1<<18;
  bf16_t* hend   = (bf16_t*)(ws + o); o += (size_t)8<<20;    // NCHK*B*DI*DS bf16
  bf16_t* aphin  = (bf16_t*)(ws + o); o += (size_t)8<<20;    // ~90 MB total

  // fused weight-convert + embed (6528 + 2048 blocks)
  k_prep<<<8576,256,0,stream>>>(ipw, w_in, xpw, w_xp, dtw, w_dt, opw, w_out,
                                x, ew, eb, h);

  for (int i=0;i<NL;i++){
    k_rms<<<B_*L_,256,0,stream>>>(h, nw + i*DM, hnorm);
    // xz(bf16) = hnorm @ in_proj^T   (M=4096,N=2048,K=512) -- 512 blocks of 128x128, BK=128
    k_g128<<<dim3(2*DI/128, B_*L_/128),256,0,stream>>>(
        hnorm, DM, w_in + (size_t)i*2*DI*DM, DM, DM, xzbf, 2*DI);
    // dbc partials = silu(conv(xz)) @ x_proj^T  (split-K x8, single pass, conv fused) -- 512 blocks
    k_dbc<<<dim3(B_*L_/64, 8),256,0,stream>>>(xzbf, cw + i*DI*DC, cb + i*DI,
                                              w_xp + (size_t)i*64*DI, dbcp, xinbf);
    // delta(bf16) = softplus(sum(partials)[:, :32] @ dt_w^T + dt_b); dbc B/C by n-block 0
    k_dt<<<dim3(DI/64, B_*L_/64),256,0,stream>>>(dbcp, w_dt + (size_t)i*DI*DTR,
                                                 dtb + i*DI, dbc, delta);
    // chunked selective scan (3-phase, LDS-staged, CHUNK=16)
    k_scan_p1<<<B_*NCHK*4,256,0,stream>>>(delta, xinbf, dbc, alog + i*DI*DS, hend, aphin);
    k_scan_p2<<<(B_*DI*DS)/256,256,0,stream>>>(hend, aphin);
    k_scan_p3<<<B_*NCHK*4,256,0,stream>>>(delta, xzbf, xinbf, dbc, alog + i*DI*DS,
                                          aphin, Dp + i*DI, ybf);
    // h += y @ out_proj^T (M=4096,N=512,K=1024) -- 512 blocks, BK=256
    k_gout64<<<dim3(DM/64, B_*L_/64),256,0,stream>>>(ybf, w_out + (size_t)i*DM*DI, h);
  }
  k_head<<<(B_*HOR)/4,256,0,stream>>>(h, hw, hb, out);
}